// Round 14
// baseline (1795.201 us; speedup 1.0000x reference)
//
#include <hip/hip_runtime.h>

#define DF 128
#define NGRAPH 8

typedef __attribute__((ext_vector_type(8))) short bf16x8;
typedef __attribute__((ext_vector_type(4))) float f32x4;

__device__ __forceinline__ float sigm(float x) { return 1.f / (1.f + __expf(-x)); }
__device__ __forceinline__ unsigned short f2bf(float f) {  // RNE f32->bf16
  unsigned u = __float_as_uint(f);
  u += 0x7FFFu + ((u >> 16) & 1u);
  return (unsigned short)(u >> 16);
}
__device__ __forceinline__ float bf2f(unsigned short u) {
  return __uint_as_float(((unsigned)u) << 16);
}
__device__ __forceinline__ float bflo(unsigned u) { return __uint_as_float(u << 16); }
__device__ __forceinline__ float bfhi(unsigned u) { return __uint_as_float(u & 0xffff0000u); }

// load 8 consecutive f32 (32B-aligned) -> bf16x8
__device__ __forceinline__ bf16x8 cvt8(const float* __restrict__ p) {
  float4 a = *(const float4*)p;
  float4 b = *(const float4*)(p + 4);
  bf16x8 r;
  r[0] = (short)f2bf(a.x); r[1] = (short)f2bf(a.y);
  r[2] = (short)f2bf(a.z); r[3] = (short)f2bf(a.w);
  r[4] = (short)f2bf(b.x); r[5] = (short)f2bf(b.y);
  r[6] = (short)f2bf(b.z); r[7] = (short)f2bf(b.w);
  return r;
}

__device__ __forceinline__ void agg_max(unsigned hv, unsigned ev, float& m0, float& m1) {
  m0 = fmaxf(m0, bflo(hv) * sigm(bflo(ev)));
  m1 = fmaxf(m1, bfhi(hv) * sigm(bfhi(ev)));
}

// ---------------- generic fill ----------------
__global__ void k_fill_u32(unsigned* __restrict__ p, unsigned v, long long n) {
  long long i = (long long)blockIdx.x * blockDim.x + threadIdx.x;
  long long st = (long long)gridDim.x * blockDim.x;
  for (; i < n; i += st) p[i] = v;
}

// ---------------- CSR build (dst-sorted edge lists) ----------------
__global__ void k_deg(const int* __restrict__ dst, unsigned* __restrict__ deg, int E) {
  int i = blockIdx.x * blockDim.x + threadIdx.x;
  int st = gridDim.x * blockDim.x;
  for (; i < E; i += st) atomicAdd(&deg[dst[i]], 1u);
}

__global__ __launch_bounds__(1024) void k_scan(
    const unsigned* __restrict__ deg, unsigned* __restrict__ rowptr,
    unsigned* __restrict__ cursor, int N) {
  __shared__ unsigned part[1024];
  int t = threadIdx.x;
  int per = (N + 1023) >> 10;
  int s0 = t * per, s1 = min(N, s0 + per);
  unsigned s = 0;
  for (int i = s0; i < s1; ++i) s += deg[i];
  part[t] = s;
  __syncthreads();
  for (int off = 1; off < 1024; off <<= 1) {
    unsigned v = (t >= off) ? part[t - off] : 0u;
    __syncthreads();
    part[t] += v;
    __syncthreads();
  }
  unsigned base = (t == 0) ? 0u : part[t - 1];
  for (int i = s0; i < s1; ++i) {
    rowptr[i] = base;
    cursor[i] = base;
    base += deg[i];
  }
  if (t == 1023) rowptr[N] = part[1023];
}

__global__ void k_scatter(const int* __restrict__ dst, unsigned* __restrict__ cursor,
                          int* __restrict__ eidb, int E) {
  int i = blockIdx.x * blockDim.x + threadIdx.x;
  int st = gridDim.x * blockDim.x;
  for (; i < E; i += st) {
    unsigned p = atomicAdd(&cursor[dst[i]], 1u);
    eidb[p] = i;
  }
}

// srcP[r] = src[eidb[r]], dstP[r] = dst[eidb[r]]
__global__ void k_permidx(const int* __restrict__ eidb, const int* __restrict__ src,
                          const int* __restrict__ dst, int* __restrict__ srcP,
                          int* __restrict__ dstP, int E) {
  int i = blockIdx.x * blockDim.x + threadIdx.x;
  int st = gridDim.x * blockDim.x;
  for (; i < E; i += st) {
    int e = eidb[i];
    srcP[i] = src[e];
    dstP[i] = dst[e];
  }
}

// ---------------- weight pre-conversion to MFMA fragment order ----------------
// 0-2 U, 3-5 V, 6-8 A, 9-11 B, 12-14 C, 15 gsw, 16 gdw, 17 Ow, 18 W1[:,128:256], 19 W1[:,256:384]
__global__ __launch_bounds__(512) void k_wconv(
    const float* __restrict__ Us, const float* __restrict__ Vs,
    const float* __restrict__ As, const float* __restrict__ Bs,
    const float* __restrict__ Cs, const float* __restrict__ gsw,
    const float* __restrict__ gdw, const float* __restrict__ Ow,
    const float* __restrict__ W1, short* __restrict__ out) {
  int b = blockIdx.x;
  const float* W;
  int ldw = DF;
  if (b < 3) W = Us + b * 16384;
  else if (b < 6) W = Vs + (b - 3) * 16384;
  else if (b < 9) W = As + (b - 6) * 16384;
  else if (b < 12) W = Bs + (b - 9) * 16384;
  else if (b < 15) W = Cs + (b - 12) * 16384;
  else if (b == 15) W = gsw;
  else if (b == 16) W = gdw;
  else if (b == 17) W = Ow;
  else if (b == 18) { W = W1 + 128; ldw = 384; }
  else { W = W1 + 256; ldw = 384; }
  short* o = out + (size_t)b * 2048 * 8;
  for (int s = threadIdx.x; s < 2048; s += 512) {
    int ct = s >> 8, ks = (s >> 6) & 3, l = s & 63;
    int row = ct * 16 + (l & 15), k0 = ks * 32 + (l >> 4) * 8;
    *(bf16x8*)&o[s * 8] = cvt8(W + (size_t)row * ldw + k0);
  }
}

// ---------------- embeddings ----------------
__global__ __launch_bounds__(128) void k_node_embed(
    const float* __restrict__ hin, const float* __restrict__ w,
    const float* __restrict__ b, float* __restrict__ h0, int rows) {
  __shared__ float Wt[64 * DF];
  __shared__ float ar[4][64];
  int tid = threadIdx.x;
  for (int i = tid; i < 64 * DF; i += 128) Wt[(i & 63) * DF + (i >> 6)] = w[i];
  float bb = b[tid];
  __syncthreads();
  for (int r0 = blockIdx.x * 4; r0 < rows; r0 += gridDim.x * 4) {
    for (int i = tid; i < 256; i += 128) ar[i >> 6][i & 63] = hin[(size_t)r0 * 64 + i];
    __syncthreads();
    float a0 = bb, a1 = bb, a2 = bb, a3 = bb;
#pragma unroll 8
    for (int k = 0; k < 64; ++k) {
      float wv = Wt[k * DF + tid];
      a0 = fmaf(ar[0][k], wv, a0); a1 = fmaf(ar[1][k], wv, a1);
      a2 = fmaf(ar[2][k], wv, a2); a3 = fmaf(ar[3][k], wv, a3);
    }
    h0[(size_t)r0 * DF + tid] = a0;
    h0[(size_t)(r0 + 1) * DF + tid] = a1;
    h0[(size_t)(r0 + 2) * DF + tid] = a2;
    h0[(size_t)(r0 + 3) * DF + tid] = a3;
    __syncthreads();
  }
}

// permuted edge embed: slot r holds edge eidb[r]
__global__ __launch_bounds__(128) void k_edge_embed(
    const float* __restrict__ ein, const int* __restrict__ eidb,
    const float* __restrict__ w, const float* __restrict__ b,
    unsigned short* __restrict__ e0u, int rows) {
  __shared__ float Wt[16 * DF];
  __shared__ float ar[4][16];
  int tid = threadIdx.x;
  for (int i = tid; i < 16 * DF; i += 128) Wt[(i & 15) * DF + (i >> 4)] = w[i];
  float bb = b[tid];
  __syncthreads();
  for (int r0 = blockIdx.x * 4; r0 < rows; r0 += gridDim.x * 4) {
    if (tid < 64) {
      int e = eidb[r0 + (tid >> 4)];
      ar[tid >> 4][tid & 15] = ein[(size_t)e * 16 + (tid & 15)];
    }
    __syncthreads();
    float a0 = bb, a1 = bb, a2 = bb, a3 = bb;
#pragma unroll
    for (int k = 0; k < 16; ++k) {
      float wv = Wt[k * DF + tid];
      a0 = fmaf(ar[0][k], wv, a0); a1 = fmaf(ar[1][k], wv, a1);
      a2 = fmaf(ar[2][k], wv, a2); a3 = fmaf(ar[3][k], wv, a3);
    }
    e0u[(size_t)r0 * DF + tid] = f2bf(a0);
    e0u[(size_t)(r0 + 1) * DF + tid] = f2bf(a1);
    e0u[(size_t)(r0 + 2) * DF + tid] = f2bf(a2);
    e0u[(size_t)(r0 + 3) * DF + tid] = f2bf(a3);
    __syncthreads();
  }
}

// ---------------- MFMA [rows,128] @ W^T (+bias), frag weights, f32 input ----------------
template <int OUTBF>
__global__ __launch_bounds__(512) void k_gemm_mfma(
    const float* __restrict__ A, const short* __restrict__ Wf,
    const float* __restrict__ bias, void* __restrict__ outv, int rows) {
  __shared__ short Wb[2048 * 8];  // 32 KB
  int tid = threadIdx.x;
  for (int s = tid; s < 2048; s += 512)
    *(bf16x8*)&Wb[s * 8] = *(const bf16x8*)&Wf[(size_t)s * 8];
  __syncthreads();
  float* outf = (float*)outv;
  unsigned short* outb = (unsigned short*)outv;
  int wid = tid >> 6, lane = tid & 63, q = lane >> 4, m = lane & 15;
  int ntiles = (rows + 127) >> 7;
  for (int t = blockIdx.x; t < ntiles; t += gridDim.x) {
    int r0 = t * 128 + wid * 16;
    int rr = r0 + m;
    if (rr >= rows) rr = rows - 1;
    const float* ap = A + (size_t)rr * DF + q * 8;
    bf16x8 a[4];
#pragma unroll
    for (int ks = 0; ks < 4; ++ks) a[ks] = cvt8(ap + 32 * ks);
#pragma unroll
    for (int ct = 0; ct < 8; ++ct) {
      f32x4 acc = {0.f, 0.f, 0.f, 0.f};
#pragma unroll
      for (int ks = 0; ks < 4; ++ks) {
        bf16x8 b = *(const bf16x8*)&Wb[((ct * 4 + ks) * 64 + lane) * 8];
        acc = __builtin_amdgcn_mfma_f32_16x16x32_bf16(a[ks], b, acc, 0, 0, 0);
      }
      int col = ct * 16 + m;
      float bb = bias ? bias[col] : 0.f;
#pragma unroll
      for (int j = 0; j < 4; ++j) {
        int row = r0 + q * 4 + j;
        if (row < rows) {
          if (OUTBF) outb[(size_t)row * DF + col] = f2bf(acc[j] + bb);
          else outf[(size_t)row * DF + col] = acc[j] + bb;
        }
      }
    }
  }
}

// same, bf16 input
__global__ __launch_bounds__(512) void k_gemmb_mfma(
    const unsigned short* __restrict__ A, const short* __restrict__ Wf,
    unsigned short* __restrict__ outb, int rows) {
  __shared__ short Wb[2048 * 8];
  int tid = threadIdx.x;
  for (int s = tid; s < 2048; s += 512)
    *(bf16x8*)&Wb[s * 8] = *(const bf16x8*)&Wf[(size_t)s * 8];
  __syncthreads();
  int wid = tid >> 6, lane = tid & 63, q = lane >> 4, m = lane & 15;
  int ntiles = (rows + 127) >> 7;
  for (int t = blockIdx.x; t < ntiles; t += gridDim.x) {
    int r0 = t * 128 + wid * 16;
    int rr = r0 + m;
    if (rr >= rows) rr = rows - 1;
    const unsigned short* ap = A + (size_t)rr * DF + q * 8;
    bf16x8 a[4];
#pragma unroll
    for (int ks = 0; ks < 4; ++ks) a[ks] = *(const bf16x8*)(ap + 32 * ks);
#pragma unroll
    for (int ct = 0; ct < 8; ++ct) {
      f32x4 acc = {0.f, 0.f, 0.f, 0.f};
#pragma unroll
      for (int ks = 0; ks < 4; ++ks) {
        bf16x8 b = *(const bf16x8*)&Wb[((ct * 4 + ks) * 64 + lane) * 8];
        acc = __builtin_amdgcn_mfma_f32_16x16x32_bf16(a[ks], b, acc, 0, 0, 0);
      }
      int col = ct * 16 + m;
#pragma unroll
      for (int j = 0; j < 4; ++j) {
        int row = r0 + q * 4 + j;
        if (row < rows) outb[(size_t)row * DF + col] = f2bf(acc[j]);
      }
    }
  }
}

// ---------------- fused 4-output node GEMM (V,U,B,C) ----------------
__global__ __launch_bounds__(512) void k_gemm4_mfma(
    const float* __restrict__ h0, const short* __restrict__ Vf,
    const short* __restrict__ Uf, const short* __restrict__ Bf,
    const short* __restrict__ Cf, unsigned short* __restrict__ hVb,
    float* __restrict__ hU, unsigned short* __restrict__ hBb,
    unsigned short* __restrict__ hCb, int rows) {
  __shared__ short Wl[4 * 2048 * 8];  // 128 KB
  int tid = threadIdx.x;
  for (int s = tid; s < 2048; s += 512) {
    *(bf16x8*)&Wl[(size_t)s * 8] = *(const bf16x8*)&Vf[(size_t)s * 8];
    *(bf16x8*)&Wl[(size_t)(2048 + s) * 8] = *(const bf16x8*)&Uf[(size_t)s * 8];
    *(bf16x8*)&Wl[(size_t)(4096 + s) * 8] = *(const bf16x8*)&Bf[(size_t)s * 8];
    *(bf16x8*)&Wl[(size_t)(6144 + s) * 8] = *(const bf16x8*)&Cf[(size_t)s * 8];
  }
  __syncthreads();
  int wid = tid >> 6, lane = tid & 63, q = lane >> 4, m = lane & 15;
  int ntiles = (rows + 127) >> 7;
  for (int t = blockIdx.x; t < ntiles; t += gridDim.x) {
    int r0 = t * 128 + wid * 16;
    int rr = r0 + m;
    if (rr >= rows) rr = rows - 1;
    const float* ap = h0 + (size_t)rr * DF + q * 8;
    bf16x8 a[4];
#pragma unroll
    for (int ks = 0; ks < 4; ++ks) a[ks] = cvt8(ap + 32 * ks);
#pragma unroll
    for (int w = 0; w < 4; ++w) {
#pragma unroll
      for (int ct = 0; ct < 8; ++ct) {
        f32x4 acc = {0.f, 0.f, 0.f, 0.f};
#pragma unroll
        for (int ks = 0; ks < 4; ++ks) {
          bf16x8 b = *(const bf16x8*)&Wl[((w * 2048) + (ct * 4 + ks) * 64 + lane) * 8];
          acc = __builtin_amdgcn_mfma_f32_16x16x32_bf16(a[ks], b, acc, 0, 0, 0);
        }
        int col = ct * 16 + m;
#pragma unroll
        for (int j = 0; j < 4; ++j) {
          int row = r0 + q * 4 + j;
          if (row < rows) {
            if (w == 1) hU[(size_t)row * DF + col] = acc[j];
            else {
              unsigned short v = f2bf(acc[j]);
              unsigned short* o = (w == 0) ? hVb : ((w == 2) ? hBb : hCb);
              o[(size_t)row * DF + col] = v;
            }
          }
        }
      }
    }
  }
}

// ======== barrier-free swapped edge passes (mfma(W, e): lane owns ONE edge) ========
#define EDGE_MFMA_BODY                                                                 \
  const unsigned short* ep = e0u + (size_t)ec * DF + q * 8;                            \
  bf16x8 bv0 = *(const bf16x8*)(ep);                                                   \
  bf16x8 bv1 = *(const bf16x8*)(ep + 32);                                              \
  bf16x8 bv2 = *(const bf16x8*)(ep + 64);                                              \
  bf16x8 bv3 = *(const bf16x8*)(ep + 96);                                              \
  f32x4 c0 = {0.f, 0.f, 0.f, 0.f}, c1 = c0, c2 = c0, c3 = c0;                          \
  f32x4 c4 = c0, c5 = c0, c6 = c0, c7 = c0;                                            \
  _Pragma("unroll") for (int ks = 0; ks < 4; ++ks) {                                   \
    bf16x8 bv = (ks == 0) ? bv0 : (ks == 1) ? bv1 : (ks == 2) ? bv2 : bv3;             \
    c0 = __builtin_amdgcn_mfma_f32_16x16x32_bf16(*(const bf16x8*)&Wb[((0 * 4 + ks) * 64 + lane) * 8], bv, c0, 0, 0, 0); \
    c1 = __builtin_amdgcn_mfma_f32_16x16x32_bf16(*(const bf16x8*)&Wb[((1 * 4 + ks) * 64 + lane) * 8], bv, c1, 0, 0, 0); \
    c2 = __builtin_amdgcn_mfma_f32_16x16x32_bf16(*(const bf16x8*)&Wb[((2 * 4 + ks) * 64 + lane) * 8], bv, c2, 0, 0, 0); \
    c3 = __builtin_amdgcn_mfma_f32_16x16x32_bf16(*(const bf16x8*)&Wb[((3 * 4 + ks) * 64 + lane) * 8], bv, c3, 0, 0, 0); \
    c4 = __builtin_amdgcn_mfma_f32_16x16x32_bf16(*(const bf16x8*)&Wb[((4 * 4 + ks) * 64 + lane) * 8], bv, c4, 0, 0, 0); \
    c5 = __builtin_amdgcn_mfma_f32_16x16x32_bf16(*(const bf16x8*)&Wb[((5 * 4 + ks) * 64 + lane) * 8], bv, c5, 0, 0, 0); \
    c6 = __builtin_amdgcn_mfma_f32_16x16x32_bf16(*(const bf16x8*)&Wb[((6 * 4 + ks) * 64 + lane) * 8], bv, c6, 0, 0, 0); \
    c7 = __builtin_amdgcn_mfma_f32_16x16x32_bf16(*(const bf16x8*)&Wb[((7 * 4 + ks) * 64 + lane) * 8], bv, c7, 0, 0, 0); \
  }

// stats pass
__global__ __launch_bounds__(512) void k_edge_xs(
    const unsigned short* __restrict__ e0u, const short* __restrict__ Af,
    const unsigned short* __restrict__ hBb, const unsigned short* __restrict__ hCb,
    const int* __restrict__ srcP, const int* __restrict__ dstP,
    float* __restrict__ stat, int Eg) {
  __shared__ short Wb[2048 * 8];  // 32 KB
  __shared__ float ls[256];
  int tid = threadIdx.x;
  for (int s = tid; s < 2048; s += 512)
    *(bf16x8*)&Wb[s * 8] = *(const bf16x8*)&Af[(size_t)s * 8];
  if (tid < 256) ls[tid] = 0.f;
  int wid = tid >> 6, lane = tid & 63, q = lane >> 4, m = lane & 15;
  int g = blockIdx.x & 7, sub = blockIdx.x >> 3, nsub = gridDim.x >> 3;
  int gbase = g * Eg, gend = gbase + Eg;
  int tpg = (Eg + 127) >> 7;
  float ps[32], pq[32];
#pragma unroll
  for (int i = 0; i < 32; ++i) { ps[i] = 0.f; pq[i] = 0.f; }
  __syncthreads();
  for (int t = sub; t < tpg; t += nsub) {
    int r0 = gbase + t * 128 + wid * 16;
    int edge = r0 + m;
    bool ok = edge < gend;
    int ec = ok ? edge : gend - 1;
    EDGE_MFMA_BODY
    if (ok) {
      int sidx = srcP[ec], didx = dstP[ec];
      const unsigned short* pb = hBb + (size_t)didx * DF + q * 4;
      const unsigned short* pc = hCb + (size_t)sidx * DF + q * 4;
#pragma unroll
      for (int ct = 0; ct < 8; ++ct) {
        f32x4 cc = (ct == 0) ? c0 : (ct == 1) ? c1 : (ct == 2) ? c2 : (ct == 3) ? c3
                   : (ct == 4) ? c4 : (ct == 5) ? c5 : (ct == 6) ? c6 : c7;
        ushort4 hb = *(const ushort4*)(pb + ct * 16);
        ushort4 hc = *(const ushort4*)(pc + ct * 16);
        float x0 = cc[0] + bf2f(hb.x) + bf2f(hc.x);
        float x1 = cc[1] + bf2f(hb.y) + bf2f(hc.y);
        float x2 = cc[2] + bf2f(hb.z) + bf2f(hc.z);
        float x3 = cc[3] + bf2f(hb.w) + bf2f(hc.w);
        ps[ct * 4 + 0] += x0; pq[ct * 4 + 0] += x0 * x0;
        ps[ct * 4 + 1] += x1; pq[ct * 4 + 1] += x1 * x1;
        ps[ct * 4 + 2] += x2; pq[ct * 4 + 2] += x2 * x2;
        ps[ct * 4 + 3] += x3; pq[ct * 4 + 3] += x3 * x3;
      }
    }
  }
#pragma unroll
  for (int i = 0; i < 32; ++i) {
    float s = ps[i], sq = pq[i];
    s += __shfl_xor(s, 1, 64); sq += __shfl_xor(sq, 1, 64);
    s += __shfl_xor(s, 2, 64); sq += __shfl_xor(sq, 2, 64);
    s += __shfl_xor(s, 4, 64); sq += __shfl_xor(sq, 4, 64);
    s += __shfl_xor(s, 8, 64); sq += __shfl_xor(sq, 8, 64);
    if (m == 0) {
      int feat = (i >> 2) * 16 + q * 4 + (i & 3);
      atomicAdd(&ls[feat], s);
      atomicAdd(&ls[128 + feat], sq);
    }
  }
  __syncthreads();
  if (tid < 128) {
    atomicAdd(&stat[512 + tid], ls[tid]);
    atomicAdd(&stat[640 + tid], ls[128 + tid]);
  }
}

// apply pass
__global__ __launch_bounds__(512) void k_edge_xa(
    unsigned short* __restrict__ e0u, const short* __restrict__ Af,
    const unsigned short* __restrict__ hBb, const unsigned short* __restrict__ hCb,
    const int* __restrict__ srcP, const int* __restrict__ dstP,
    const float* __restrict__ stat, int Eg) {
  __shared__ short Wb[2048 * 8];  // 32 KB
  int tid = threadIdx.x;
  for (int s = tid; s < 2048; s += 512)
    *(bf16x8*)&Wb[s * 8] = *(const bf16x8*)&Af[(size_t)s * 8];
  int wid = tid >> 6, lane = tid & 63, q = lane >> 4, m = lane & 15;
  float mm[32], iv[32];
#pragma unroll
  for (int ct = 0; ct < 8; ++ct)
#pragma unroll
    for (int j = 0; j < 4; ++j) {
      int f = ct * 16 + q * 4 + j;
      mm[ct * 4 + j] = stat[768 + f];
      iv[ct * 4 + j] = stat[896 + f];
    }
  int g = blockIdx.x & 7, sub = blockIdx.x >> 3, nsub = gridDim.x >> 3;
  int gbase = g * Eg, gend = gbase + Eg;
  int tpg = (Eg + 127) >> 7;
  __syncthreads();
  for (int t = sub; t < tpg; t += nsub) {
    int r0 = gbase + t * 128 + wid * 16;
    int edge = r0 + m;
    bool ok = edge < gend;
    int ec = ok ? edge : gend - 1;
    EDGE_MFMA_BODY
    if (ok) {
      int sidx = srcP[ec], didx = dstP[ec];
      const unsigned short* pb = hBb + (size_t)didx * DF + q * 4;
      const unsigned short* pc = hCb + (size_t)sidx * DF + q * 4;
      unsigned short* pe = e0u + (size_t)ec * DF + q * 4;
#pragma unroll
      for (int ct = 0; ct < 8; ++ct) {
        f32x4 cc = (ct == 0) ? c0 : (ct == 1) ? c1 : (ct == 2) ? c2 : (ct == 3) ? c3
                   : (ct == 4) ? c4 : (ct == 5) ? c5 : (ct == 6) ? c6 : c7;
        ushort4 hb = *(const ushort4*)(pb + ct * 16);
        ushort4 hc = *(const ushort4*)(pc + ct * 16);
        ushort4 eo = *(const ushort4*)(pe + ct * 16);
        float x0 = cc[0] + bf2f(hb.x) + bf2f(hc.x);
        float x1 = cc[1] + bf2f(hb.y) + bf2f(hc.y);
        float x2 = cc[2] + bf2f(hb.z) + bf2f(hc.z);
        float x3 = cc[3] + bf2f(hb.w) + bf2f(hc.w);
        ushort4 nv;
        nv.x = f2bf(bf2f(eo.x) + fmaxf((x0 - mm[ct * 4 + 0]) * iv[ct * 4 + 0], 0.f));
        nv.y = f2bf(bf2f(eo.y) + fmaxf((x1 - mm[ct * 4 + 1]) * iv[ct * 4 + 1], 0.f));
        nv.z = f2bf(bf2f(eo.z) + fmaxf((x2 - mm[ct * 4 + 2]) * iv[ct * 4 + 2], 0.f));
        nv.w = f2bf(bf2f(eo.w) + fmaxf((x3 - mm[ct * 4 + 3]) * iv[ct * 4 + 3], 0.f));
        *(ushort4*)(pe + ct * 16) = nv;
      }
    }
  }
}

// ---------------- node-major segment max (CSR-streamed e0u, 8-way ILP) ----------------
__global__ __launch_bounds__(512) void k_node_agg(
    float* __restrict__ hU, const unsigned short* __restrict__ hVb,
    const unsigned short* __restrict__ e0u, const int* __restrict__ srcP,
    const unsigned* __restrict__ rowptr, float* __restrict__ stat, int Ngr) {
  __shared__ float sr[4][512];
  int tid = threadIdx.x, wid = tid >> 6, lane = tid & 63;
  int g = blockIdx.x & 7, sub = blockIdx.x >> 3, nsub = gridDim.x >> 3;
  float ps0 = 0.f, ps1 = 0.f, pq0 = 0.f, pq1 = 0.f;
  for (int nn = sub * 8 + wid; nn < Ngr; nn += nsub * 8) {
    int n = g * Ngr + nn;
    unsigned r0 = rowptr[n], r1 = rowptr[n + 1];
    float m0 = -3.4e38f, m1 = -3.4e38f;
    for (unsigned rc = r0; rc < r1; rc += 64) {
      int batch = (int)min(64u, r1 - rc);
      int myS = srcP[rc + ((lane < batch) ? lane : 0)];
      int j = 0;
      for (; j + 8 <= batch; j += 8) {
        int s0 = __shfl(myS, j, 64), s1 = __shfl(myS, j + 1, 64);
        int s2 = __shfl(myS, j + 2, 64), s3 = __shfl(myS, j + 3, 64);
        int s4 = __shfl(myS, j + 4, 64), s5 = __shfl(myS, j + 5, 64);
        int s6 = __shfl(myS, j + 6, 64), s7 = __shfl(myS, j + 7, 64);
        unsigned h0v = *(const unsigned*)&hVb[(size_t)s0 * DF + 2 * lane];
        unsigned h1v = *(const unsigned*)&hVb[(size_t)s1 * DF + 2 * lane];
        unsigned h2v = *(const unsigned*)&hVb[(size_t)s2 * DF + 2 * lane];
        unsigned h3v = *(const unsigned*)&hVb[(size_t)s3 * DF + 2 * lane];
        unsigned h4v = *(const unsigned*)&hVb[(size_t)s4 * DF + 2 * lane];
        unsigned h5v = *(const unsigned*)&hVb[(size_t)s5 * DF + 2 * lane];
        unsigned h6v = *(const unsigned*)&hVb[(size_t)s6 * DF + 2 * lane];
        unsigned h7v = *(const unsigned*)&hVb[(size_t)s7 * DF + 2 * lane];
        unsigned v0 = *(const unsigned*)&e0u[(size_t)(rc + j) * DF + 2 * lane];
        unsigned v1 = *(const unsigned*)&e0u[(size_t)(rc + j + 1) * DF + 2 * lane];
        unsigned v2 = *(const unsigned*)&e0u[(size_t)(rc + j + 2) * DF + 2 * lane];
        unsigned v3 = *(const unsigned*)&e0u[(size_t)(rc + j + 3) * DF + 2 * lane];
        unsigned v4 = *(const unsigned*)&e0u[(size_t)(rc + j + 4) * DF + 2 * lane];
        unsigned v5 = *(const unsigned*)&e0u[(size_t)(rc + j + 5) * DF + 2 * lane];
        unsigned v6 = *(const unsigned*)&e0u[(size_t)(rc + j + 6) * DF + 2 * lane];
        unsigned v7 = *(const unsigned*)&e0u[(size_t)(rc + j + 7) * DF + 2 * lane];
        agg_max(h0v, v0, m0, m1);
        agg_max(h1v, v1, m0, m1);
        agg_max(h2v, v2, m0, m1);
        agg_max(h3v, v3, m0, m1);
        agg_max(h4v, v4, m0, m1);
        agg_max(h5v, v5, m0, m1);
        agg_max(h6v, v6, m0, m1);
        agg_max(h7v, v7, m0, m1);
      }
      for (; j < batch; ++j) {
        int s = __shfl(myS, j, 64);
        unsigned hv = *(const unsigned*)&hVb[(size_t)s * DF + 2 * lane];
        unsigned ev = *(const unsigned*)&e0u[(size_t)(rc + j) * DF + 2 * lane];
        agg_max(hv, ev, m0, m1);
      }
    }
    if (r1 == r0) { m0 = 0.f; m1 = 0.f; }
    size_t idx = (size_t)n * DF + 2 * lane;
    float2 hu = *(float2*)&hU[idx];
    float t0 = hu.x + m0, t1 = hu.y + m1;
    hu.x = t0; hu.y = t1;
    *(float2*)&hU[idx] = hu;
    ps0 += t0; ps1 += t1;
    pq0 += t0 * t0; pq1 += t1 * t1;
  }
  sr[0][tid] = ps0; sr[1][tid] = ps1; sr[2][tid] = pq0; sr[3][tid] = pq1;
  __syncthreads();
  if (tid < 64) {
    float a0 = 0.f, a1 = 0.f, b0 = 0.f, b1 = 0.f;
#pragma unroll
    for (int w = 0; w < 8; ++w) {
      a0 += sr[0][w * 64 + tid]; a1 += sr[1][w * 64 + tid];
      b0 += sr[2][w * 64 + tid]; b1 += sr[3][w * 64 + tid];
    }
    atomicAdd(&stat[2 * tid], a0);
    atomicAdd(&stat[2 * tid + 1], a1);
    atomicAdd(&stat[128 + 2 * tid], b0);
    atomicAdd(&stat[128 + 2 * tid + 1], b1);
  }
}

// finalize BN stats
__global__ void k_bn_finalize(float* __restrict__ stat, float nN, float nE) {
  int tid = threadIdx.x;
  if (tid < 128) {
    float mean = stat[tid] / nN;
    float var = stat[128 + tid] / nN - mean * mean;
    stat[256 + tid] = mean;
    stat[384 + tid] = rsqrtf(fmaxf(var, 0.f) + 1e-5f);
  } else {
    int d = tid - 128;
    float mean = stat[512 + d] / nE;
    float var = stat[640 + d] / nE - mean * mean;
    stat[768 + d] = mean;
    stat[896 + d] = rsqrtf(fmaxf(var, 0.f) + 1e-5f);
  }
}

__global__ __launch_bounds__(256) void k_node_update(
    float* __restrict__ h0, const float* __restrict__ hU,
    const float* __restrict__ stat, long long total) {
  long long i = (long long)blockIdx.x * blockDim.x + threadIdx.x;
  long long st = (long long)gridDim.x * blockDim.x;
  for (; i < total; i += st) {
    int d = (int)(i & 127);
    float t = (hU[i] - stat[256 + d]) * stat[384 + d];
    h0[i] += fmaxf(t, 0.f);
  }
}

// ---------------- GATv2 score (permuted edge-major) ----------------
__global__ __launch_bounds__(256) void k_gat_score(
    const unsigned short* __restrict__ fsb, const unsigned short* __restrict__ fdb,
    const int* __restrict__ srcP, const int* __restrict__ dstP,
    const float* __restrict__ attn, float* __restrict__ score, int E) {
  long long i = (long long)blockIdx.x * blockDim.x + threadIdx.x;
  long long st = (long long)gridDim.x * blockDim.x;
  long long total = (long long)E * 8;
  for (; i < total; i += st) {
    int e = (int)(i >> 3), mh = (int)(i & 7);
    int s = srcP[e], dn = dstP[e];
    const unsigned short* ps = fsb + (size_t)s * DF + mh * 16;
    const unsigned short* pd = fdb + (size_t)dn * DF + mh * 16;
    const float* pa = attn + mh * 16;
    bf16x8 s0 = *(const bf16x8*)ps;
    bf16x8 s1 = *(const bf16x8*)(ps + 8);
    bf16x8 d0 = *(const bf16x8*)pd;
    bf16x8 d1 = *(const bf16x8*)(pd + 8);
    float acc = 0.f;
#pragma unroll
    for (int kk = 0; kk < 8; ++kk) {
      float z = bf2f((unsigned short)s0[kk]) + bf2f((unsigned short)d0[kk]);
      z = (z > 0.f) ? z : 0.2f * z;
      acc = fmaf(z, pa[kk], acc);
      float z2 = bf2f((unsigned short)s1[kk]) + bf2f((unsigned short)d1[kk]);
      z2 = (z2 > 0.f) ? z2 : 0.2f * z2;
      acc = fmaf(z2, pa[kk + 8], acc);
    }
    score[i] = acc;
  }
}

// ---------------- GATv2 node reduction (streamed scores, 8-way ILP) ----------------
__global__ __launch_bounds__(256) void k_gat_node(
    const float* __restrict__ score, const unsigned short* __restrict__ fsb,
    const int* __restrict__ srcP, const unsigned* __restrict__ rowptr,
    float* __restrict__ rst, int Ngr) {
  int tid = threadIdx.x, wid = tid >> 6, lane = tid & 63;
  int g = blockIdx.x & 7, sub = blockIdx.x >> 3, nsub = gridDim.x >> 3;
  int head = lane >> 3, slot = lane & 7;
  for (int nn = sub * 4 + wid; nn < Ngr; nn += nsub * 4) {
    int n = g * Ngr + nn;
    unsigned r0 = rowptr[n], r1 = rowptr[n + 1];
    float hm = -3.4e38f;
    for (unsigned r = r0 + slot; r < r1; r += 8)
      hm = fmaxf(hm, score[(size_t)r * 8 + head]);
#pragma unroll
    for (int mk = 1; mk < 8; mk <<= 1) hm = fmaxf(hm, __shfl_xor(hm, mk, 64));
    float dn = 0.f;
    for (unsigned r = r0 + slot; r < r1; r += 8)
      dn += __expf(score[(size_t)r * 8 + head] - hm);
#pragma unroll
    for (int mk = 1; mk < 8; mk <<= 1) dn += __shfl_xor(dn, mk, 64);
    float inv = (r1 > r0) ? 1.f / dn : 0.f;
    float a0 = 0.f, a1 = 0.f;
    for (unsigned rc = r0; rc < r1; rc += 64) {
      int batch = (int)min(64u, r1 - rc);
      int myS = srcP[rc + ((lane < batch) ? lane : 0)];
      int j = 0;
      for (; j + 8 <= batch; j += 8) {
        int s0 = __shfl(myS, j, 64), s1 = __shfl(myS, j + 1, 64);
        int s2 = __shfl(myS, j + 2, 64), s3 = __shfl(myS, j + 3, 64);
        int s4 = __shfl(myS, j + 4, 64), s5 = __shfl(myS, j + 5, 64);
        int s6 = __shfl(myS, j + 6, 64), s7 = __shfl(myS, j + 7, 64);
        float sc0 = score[(size_t)(rc + j) * 8 + head];
        float sc1 = score[(size_t)(rc + j + 1) * 8 + head];
        float sc2 = score[(size_t)(rc + j + 2) * 8 + head];
        float sc3 = score[(size_t)(rc + j + 3) * 8 + head];
        float sc4 = score[(size_t)(rc + j + 4) * 8 + head];
        float sc5 = score[(size_t)(rc + j + 5) * 8 + head];
        float sc6 = score[(size_t)(rc + j + 6) * 8 + head];
        float sc7 = score[(size_t)(rc + j + 7) * 8 + head];
        unsigned f0 = *(const unsigned*)&fsb[(size_t)s0 * DF + 2 * lane];
        unsigned f1 = *(const unsigned*)&fsb[(size_t)s1 * DF + 2 * lane];
        unsigned f2 = *(const unsigned*)&fsb[(size_t)s2 * DF + 2 * lane];
        unsigned f3 = *(const unsigned*)&fsb[(size_t)s3 * DF + 2 * lane];
        unsigned f4 = *(const unsigned*)&fsb[(size_t)s4 * DF + 2 * lane];
        unsigned f5 = *(const unsigned*)&fsb[(size_t)s5 * DF + 2 * lane];
        unsigned f6 = *(const unsigned*)&fsb[(size_t)s6 * DF + 2 * lane];
        unsigned f7 = *(const unsigned*)&fsb[(size_t)s7 * DF + 2 * lane];
        float w0 = __expf(sc0 - hm) * inv, w1 = __expf(sc1 - hm) * inv;
        float w2 = __expf(sc2 - hm) * inv, w3 = __expf(sc3 - hm) * inv;
        float w4 = __expf(sc4 - hm) * inv, w5 = __expf(sc5 - hm) * inv;
        float w6 = __expf(sc6 - hm) * inv, w7 = __expf(sc7 - hm) * inv;
        a0 = fmaf(w0, bflo(f0), a0); a1 = fmaf(w0, bfhi(f0), a1);
        a0 = fmaf(w1, bflo(f1), a0); a1 = fmaf(w1, bfhi(f1), a1);
        a0 = fmaf(w2, bflo(f2), a0); a1 = fmaf(w2, bfhi(f2), a1);
        a0 = fmaf(w3, bflo(f3), a0); a1 = fmaf(w3, bfhi(f3), a1);
        a0 = fmaf(w4, bflo(f4), a0); a1 = fmaf(w4, bfhi(f4), a1);
        a0 = fmaf(w5, bflo(f5), a0); a1 = fmaf(w5, bfhi(f5), a1);
        a0 = fmaf(w6, bflo(f6), a0); a1 = fmaf(w6, bfhi(f6), a1);
        a0 = fmaf(w7, bflo(f7), a0); a1 = fmaf(w7, bfhi(f7), a1);
      }
      for (; j < batch; ++j) {
        int s = __shfl(myS, j, 64);
        float w = __expf(score[(size_t)(rc + j) * 8 + head] - hm) * inv;
        unsigned fv = *(const unsigned*)&fsb[(size_t)s * DF + 2 * lane];
        a0 = fmaf(w, bflo(fv), a0);
        a1 = fmaf(w, bfhi(fv), a1);
      }
    }
    float2 o;
    o.x = a0; o.y = a1;
    *(float2*)&rst[(size_t)n * DF + 2 * lane] = o;
  }
}

// bias2 = O_b + gat_bias @ O_w^T
__global__ void k_bias2(const float* __restrict__ gat_bias,
                        const float* __restrict__ O_w,
                        const float* __restrict__ O_b, float* __restrict__ bias2) {
  int d = threadIdx.x;
  float acc = O_b[d];
  for (int k = 0; k < DF; ++k) acc = fmaf(gat_bias[k], O_w[(size_t)d * DF + k], acc);
  bias2[d] = acc;
}

// ---------------- readout ----------------
__global__ __launch_bounds__(128) void k_moy(
    const unsigned short* __restrict__ h2b, const int* __restrict__ ng,
    float* __restrict__ moy, float* __restrict__ cnt, int rows) {
  int tid = threadIdx.x;
  int per = (rows + gridDim.x - 1) / gridDim.x;
  int n0 = blockIdx.x * per;
  int n1 = min(rows, n0 + per);
  if (n0 >= n1) return;
  int cur = ng[n0];
  float acc = 0.f; int c = 0;
  for (int n = n0; n < n1; ++n) {
    int g = ng[n];
    if (g != cur) {
      atomicAdd(&moy[cur * DF + tid], acc);
      if (tid == 0) atomicAdd(&cnt[cur], (float)c);
      acc = 0.f; c = 0; cur = g;
    }
    acc += bf2f(h2b[(size_t)n * DF + tid]);
    ++c;
  }
  atomicAdd(&moy[cur * DF + tid], acc);
  if (tid == 0) atomicAdd(&cnt[cur], (float)c);
}

// P0[g] = W1[:,0:128] @ (moy_sum[g]/cnt[g]) + W1_b
__global__ void k_p0(const float* __restrict__ W1, const float* __restrict__ W1b_,
                     const float* __restrict__ moy, const float* __restrict__ cnt,
                     float* __restrict__ P0) {
  int g = blockIdx.x, d = threadIdx.x;
  float inv = 1.f / cnt[g];
  float acc = W1b_[d];
  for (int k = 0; k < DF; ++k) acc = fmaf(W1[(size_t)d * 384 + k], moy[g * DF + k] * inv, acc);
  P0[g * DF + d] = acc;
}

// ---------------- CSR head (permuted; out scatter via eidb) ----------------
__global__ __launch_bounds__(256) void k_head(
    const unsigned short* __restrict__ P1b, const unsigned short* __restrict__ P2b,
    const float* __restrict__ P0, const int* __restrict__ srcP,
    const unsigned* __restrict__ rowptr, const int* __restrict__ eidb,
    const float* __restrict__ W2, const float* __restrict__ W2b,
    float* __restrict__ out, int Ngr) {
  int tid = threadIdx.x, wid = tid >> 6, lane = tid & 63;
  int g = blockIdx.x & 7, sub = blockIdx.x >> 3, nsub = gridDim.x >> 3;
  float w2b = W2b[0];
  float w20 = W2[2 * lane], w21 = W2[2 * lane + 1];
  float b0 = P0[g * DF + 2 * lane], b1v = P0[g * DF + 2 * lane + 1];
  for (int nn = sub * 4 + wid; nn < Ngr; nn += nsub * 4) {
    int n = g * Ngr + nn;
    unsigned r0 = rowptr[n], r1 = rowptr[n + 1];
    if (r1 == r0) continue;
    unsigned p2 = *(const unsigned*)&P2b[(size_t)n * DF + 2 * lane];
    float base0 = b0 + bflo(p2);
    float base1 = b1v + bfhi(p2);
    for (unsigned rc = r0; rc < r1; rc += 64) {
      int cnt2 = (int)min(64u, r1 - rc);
      int myE = eidb[rc + ((lane < cnt2) ? lane : 0)];
      int myS = srcP[rc + ((lane < cnt2) ? lane : 0)];
      int j = 0;
      for (; j + 4 <= cnt2; j += 4) {
        int e0 = __shfl(myE, j, 64), e1 = __shfl(myE, j + 1, 64);
        int e2 = __shfl(myE, j + 2, 64), e3 = __shfl(myE, j + 3, 64);
        int s0 = __shfl(myS, j, 64), s1 = __shfl(myS, j + 1, 64);
        int s2 = __shfl(myS, j + 2, 64), s3 = __shfl(myS, j + 3, 64);
        unsigned u0 = *(const unsigned*)&P1b[(size_t)s0 * DF + 2 * lane];
        unsigned u1 = *(const unsigned*)&P1b[(size_t)s1 * DF + 2 * lane];
        unsigned u2 = *(const unsigned*)&P1b[(size_t)s2 * DF + 2 * lane];
        unsigned u3 = *(const unsigned*)&P1b[(size_t)s3 * DF + 2 * lane];
        float v0 = fmaxf(base0 + bflo(u0), 0.f) * w20 + fmaxf(base1 + bfhi(u0), 0.f) * w21;
        float v1 = fmaxf(base0 + bflo(u1), 0.f) * w20 + fmaxf(base1 + bfhi(u1), 0.f) * w21;
        float v2 = fmaxf(base0 + bflo(u2), 0.f) * w20 + fmaxf(base1 + bfhi(u2), 0.f) * w21;
        float v3 = fmaxf(base0 + bflo(u3), 0.f) * w20 + fmaxf(base1 + bfhi(u3), 0.f) * w21;
#pragma unroll
        for (int mk = 1; mk < 64; mk <<= 1) {
          v0 += __shfl_xor(v0, mk, 64);
          v1 += __shfl_xor(v1, mk, 64);
          v2 += __shfl_xor(v2, mk, 64);
          v3 += __shfl_xor(v3, mk, 64);
        }
        if (lane == 0) {
          out[e0] = sigm(v0 + w2b);
          out[e1] = sigm(v1 + w2b);
          out[e2] = sigm(v2 + w2b);
          out[e3] = sigm(v3 + w2b);
        }
      }
      for (; j < cnt2; ++j) {
        int e = __shfl(myE, j, 64);
        int s = __shfl(myS, j, 64);
        unsigned p1 = *(const unsigned*)&P1b[(size_t)s * DF + 2 * lane];
        float v = fmaxf(base0 + bflo(p1), 0.f) * w20 + fmaxf(base1 + bfhi(p1), 0.f) * w21;
#pragma unroll
        for (int mk = 1; mk < 64; mk <<= 1) v += __shfl_xor(v, mk, 64);
        if (lane == 0) out[e] = sigm(v + w2b);
      }
    }
  }
}

extern "C" void kernel_launch(void* const* d_in, const int* in_sizes, int n_in,
                              void* d_out, int out_size, void* d_ws, size_t ws_size,
                              hipStream_t stream) {
  const float* h_in = (const float*)d_in[0];
  const float* e_in = (const float*)d_in[1];
  const int* src = (const int*)d_in[2];
  const int* dst = (const int*)d_in[3];
  const int* node_graph = (const int*)d_in[4];
  const float* emb_n_w = (const float*)d_in[6];
  const float* emb_n_b = (const float*)d_in[7];
  const float* emb_e_w = (const float*)d_in[8];
  const float* emb_e_b = (const float*)d_in[9];
  const float* Us = (const float*)d_in[10];
  const float* Vs = (const float*)d_in[11];
  const float* As = (const float*)d_in[12];
  const float* Bs = (const float*)d_in[13];
  const float* Cs = (const float*)d_in[14];
  const float* gat_src_w = (const float*)d_in[15];
  const float* gat_src_b = (const float*)d_in[16];
  const float* gat_dst_w = (const float*)d_in[17];
  const float* gat_dst_b = (const float*)d_in[18];
  const float* gat_attn = (const float*)d_in[19];
  const float* gat_bias = (const float*)d_in[20];
  const float* O_w = (const float*)d_in[21];
  const float* O_b = (const float*)d_in[22];
  const float* W1_w = (const float*)d_in[23];
  const float* W1_b = (const float*)d_in[24];
  const float* W2_w = (const float*)d_in[25];
  const float* W2_b = (const float*)d_in[26];
  float* out = (float*)d_out;

  const int N = in_sizes[0] / 64;   // 30000
  const int E = in_sizes[1] / 16;   // 360000
  const int Eg = E / NGRAPH;        // 45000
  const int Ngr = N / NGRAPH;       // 3750

  auto rnd = [](size_t b) { return (b + 255) & ~(size_t)255; };
  const size_t sz_e0 = rnd((size_t)E * DF * 2);
  const size_t sz_node = rnd((size_t)N * DF * 4);
  const size_t sz_nodeb = rnd((size_t)N * DF * 2);
  const size_t sz_score = rnd((size_t)E * 8 * 4);
  const size_t sz_wfrag = rnd(20 * 2048 * 8 * 2);
  const size_t sz_rp = rnd((size_t)(N + 1) * 4);
  const size_t sz_eid = rnd((size_t)E * 4);
  const size_t sz_misc = rnd(4096 * 4);
  const size_t needed = sz_e0 + 3 * sz_node + 4 * sz_nodeb + sz_score + sz_wfrag +
                        3 * sz_rp + 3 * sz_eid + sz_misc;
  if (ws_size < needed) {
    k_fill_u32<<<256, 256, 0, stream>>>((unsigned*)out, 0xBF800000u, (long long)out_size);
    return;
  }

  char* wp = (char*)d_ws;
  auto alloc = [&](size_t bytes) { void* p = wp; wp += bytes; return p; };
  unsigned short* e0u = (unsigned short*)alloc(sz_e0);
  float* h0 = (float*)alloc(sz_node);
  float* hU = (float*)alloc(sz_node);
  float* rst = (float*)alloc(sz_node);
  unsigned short* hVb = (unsigned short*)alloc(sz_nodeb);
  unsigned short* hBb = (unsigned short*)alloc(sz_nodeb);
  unsigned short* hCb = (unsigned short*)alloc(sz_nodeb);
  unsigned short* h2b = (unsigned short*)alloc(sz_nodeb);
  float* score = (float*)alloc(sz_score);
  short* wfrag = (short*)alloc(sz_wfrag);
  unsigned* rowptr = (unsigned*)alloc(sz_rp);
  unsigned* cursor = (unsigned*)alloc(sz_rp);
  unsigned* deg = (unsigned*)alloc(sz_rp);
  int* eidb = (int*)alloc(sz_eid);
  int* srcP = (int*)alloc(sz_eid);
  int* dstP = (int*)alloc(sz_eid);
  float* misc = (float*)alloc(sz_misc);
  float* stat = misc;                                     // [0,1024)
  float* bias2 = misc + 1024;                             // [1024,1152)
  float* moy = misc + 1152;                               // [1152,2176)
  float* cnt = misc + 2176;                               // [2176,2184)
  float* P0 = misc + 2304;                                // [2304,3328)
  unsigned short* P1b = e0u;  // alias: e0u dead after last layer
  unsigned short* P2b = e0u + (size_t)N * DF;

  auto WF = [&](int idx) { return wfrag + (size_t)idx * 2048 * 8; };

  // CSR build + permuted indices
  k_fill_u32<<<64, 256, 0, stream>>>(deg, 0u, N);
  k_deg<<<512, 256, 0, stream>>>(dst, deg, E);
  k_scan<<<1, 1024, 0, stream>>>(deg, rowptr, cursor, N);
  k_scatter<<<512, 256, 0, stream>>>(dst, cursor, eidb, E);
  k_permidx<<<512, 256, 0, stream>>>(eidb, src, dst, srcP, dstP, E);

  k_wconv<<<20, 512, 0, stream>>>(Us, Vs, As, Bs, Cs, gat_src_w, gat_dst_w, O_w,
                                  W1_w, wfrag);

  const int gN = (N + 127) / 128;
  k_node_embed<<<2048, 128, 0, stream>>>(h_in, emb_n_w, emb_n_b, h0, N);
  k_edge_embed<<<4096, 128, 0, stream>>>(e_in, eidb, emb_e_w, emb_e_b, e0u, E);

  for (int l = 0; l < 3; ++l) {
    k_gemm4_mfma<<<gN, 512, 0, stream>>>(h0, WF(3 + l), WF(l), WF(9 + l), WF(12 + l),
                                         hVb, hU, hBb, hCb, N);
    k_fill_u32<<<4, 256, 0, stream>>>((unsigned*)stat, 0u, 1024);
    k_node_agg<<<4096, 512, 0, stream>>>(hU, hVb, e0u, srcP, rowptr, stat, Ngr);
    k_edge_xs<<<2048, 512, 0, stream>>>(e0u, WF(6 + l), hBb, hCb, srcP, dstP, stat, Eg);
    k_bn_finalize<<<1, 256, 0, stream>>>(stat, (float)N, (float)E);
    k_node_update<<<2048, 256, 0, stream>>>(h0, hU, stat, (long long)N * DF);
    k_edge_xa<<<2048, 512, 0, stream>>>(e0u, WF(6 + l), hBb, hCb, srcP, dstP, stat, Eg);
  }

  // GATv2: fs -> hVb, fd -> hBb
  k_gemm_mfma<1><<<gN, 512, 0, stream>>>(h0, WF(15), gat_src_b, hVb, N);
  k_gemm_mfma<1><<<gN, 512, 0, stream>>>(h0, WF(16), gat_dst_b, hBb, N);
  k_gat_score<<<2048, 256, 0, stream>>>(hVb, hBb, srcP, dstP, gat_attn, score, E);
  k_gat_node<<<4096, 256, 0, stream>>>(score, hVb, srcP, rowptr, rst, Ngr);
  k_bias2<<<1, 128, 0, stream>>>(gat_bias, O_w, O_b, bias2);
  k_gemm_mfma<1><<<gN, 512, 0, stream>>>(rst, WF(17), bias2, h2b, N);  // h2

  // readout + decomposed head
  k_fill_u32<<<2, 256, 0, stream>>>((unsigned*)moy, 0u, 1032);
  k_moy<<<128, 128, 0, stream>>>(h2b, node_graph, moy, cnt, N);
  k_p0<<<8, 128, 0, stream>>>(W1_w, W1_b, moy, cnt, P0);
  k_gemmb_mfma<<<gN, 512, 0, stream>>>(h2b, WF(18), P1b, N);
  k_gemmb_mfma<<<gN, 512, 0, stream>>>(h2b, WF(19), P2b, N);
  k_head<<<2048, 256, 0, stream>>>(P1b, P2b, P0, srcP, rowptr, eidb, W2_w, W2_b,
                                   out, Ngr);
}

// Round 15
// 1387.565 us; speedup vs baseline: 1.2938x; 1.2938x over previous
//
#include <hip/hip_runtime.h>

#define DF 128
#define NGRAPH 8

typedef __attribute__((ext_vector_type(8))) short bf16x8;
typedef __attribute__((ext_vector_type(4))) float f32x4;

__device__ __forceinline__ float sigm(float x) { return 1.f / (1.f + __expf(-x)); }
__device__ __forceinline__ unsigned short f2bf(float f) {  // RNE f32->bf16
  unsigned u = __float_as_uint(f);
  u += 0x7FFFu + ((u >> 16) & 1u);
  return (unsigned short)(u >> 16);
}
__device__ __forceinline__ float bf2f(unsigned short u) {
  return __uint_as_float(((unsigned)u) << 16);
}
__device__ __forceinline__ float bflo(unsigned u) { return __uint_as_float(u << 16); }
__device__ __forceinline__ float bfhi(unsigned u) { return __uint_as_float(u & 0xffff0000u); }

// load 8 consecutive f32 (32B-aligned) -> bf16x8
__device__ __forceinline__ bf16x8 cvt8(const float* __restrict__ p) {
  float4 a = *(const float4*)p;
  float4 b = *(const float4*)(p + 4);
  bf16x8 r;
  r[0] = (short)f2bf(a.x); r[1] = (short)f2bf(a.y);
  r[2] = (short)f2bf(a.z); r[3] = (short)f2bf(a.w);
  r[4] = (short)f2bf(b.x); r[5] = (short)f2bf(b.y);
  r[6] = (short)f2bf(b.z); r[7] = (short)f2bf(b.w);
  return r;
}

__device__ __forceinline__ void agg_max(unsigned hv, unsigned ev, float& m0, float& m1) {
  m0 = fmaxf(m0, bflo(hv) * sigm(bflo(ev)));
  m1 = fmaxf(m1, bfhi(hv) * sigm(bfhi(ev)));
}

// ---------------- generic fill ----------------
__global__ void k_fill_u32(unsigned* __restrict__ p, unsigned v, long long n) {
  long long i = (long long)blockIdx.x * blockDim.x + threadIdx.x;
  long long st = (long long)gridDim.x * blockDim.x;
  for (; i < n; i += st) p[i] = v;
}

// ---------------- CSR build (dst-sorted edge lists) ----------------
__global__ void k_deg(const int* __restrict__ dst, unsigned* __restrict__ deg, int E) {
  int i = blockIdx.x * blockDim.x + threadIdx.x;
  int st = gridDim.x * blockDim.x;
  for (; i < E; i += st) atomicAdd(&deg[dst[i]], 1u);
}

__global__ __launch_bounds__(1024) void k_scan(
    const unsigned* __restrict__ deg, unsigned* __restrict__ rowptr,
    unsigned* __restrict__ cursor, int N) {
  __shared__ unsigned part[1024];
  int t = threadIdx.x;
  int per = (N + 1023) >> 10;
  int s0 = t * per, s1 = min(N, s0 + per);
  unsigned s = 0;
  for (int i = s0; i < s1; ++i) s += deg[i];
  part[t] = s;
  __syncthreads();
  for (int off = 1; off < 1024; off <<= 1) {
    unsigned v = (t >= off) ? part[t - off] : 0u;
    __syncthreads();
    part[t] += v;
    __syncthreads();
  }
  unsigned base = (t == 0) ? 0u : part[t - 1];
  for (int i = s0; i < s1; ++i) {
    rowptr[i] = base;
    cursor[i] = base;
    base += deg[i];
  }
  if (t == 1023) rowptr[N] = part[1023];
}

__global__ void k_scatter(const int* __restrict__ dst, unsigned* __restrict__ cursor,
                          int* __restrict__ eidb, int E) {
  int i = blockIdx.x * blockDim.x + threadIdx.x;
  int st = gridDim.x * blockDim.x;
  for (; i < E; i += st) {
    unsigned p = atomicAdd(&cursor[dst[i]], 1u);
    eidb[p] = i;
  }
}

// srcP[r] = src[eidb[r]], dstP[r] = dst[eidb[r]]
__global__ void k_permidx(const int* __restrict__ eidb, const int* __restrict__ src,
                          const int* __restrict__ dst, int* __restrict__ srcP,
                          int* __restrict__ dstP, int E) {
  int i = blockIdx.x * blockDim.x + threadIdx.x;
  int st = gridDim.x * blockDim.x;
  for (; i < E; i += st) {
    int e = eidb[i];
    srcP[i] = src[e];
    dstP[i] = dst[e];
  }
}

// ---------------- weight pre-conversion to MFMA fragment order ----------------
// 0-2 U, 3-5 V, 6-8 A, 9-11 B, 12-14 C, 15 gsw, 16 gdw, 17 Ow, 18 W1[:,128:256], 19 W1[:,256:384]
__global__ __launch_bounds__(512) void k_wconv(
    const float* __restrict__ Us, const float* __restrict__ Vs,
    const float* __restrict__ As, const float* __restrict__ Bs,
    const float* __restrict__ Cs, const float* __restrict__ gsw,
    const float* __restrict__ gdw, const float* __restrict__ Ow,
    const float* __restrict__ W1, short* __restrict__ out) {
  int b = blockIdx.x;
  const float* W;
  int ldw = DF;
  if (b < 3) W = Us + b * 16384;
  else if (b < 6) W = Vs + (b - 3) * 16384;
  else if (b < 9) W = As + (b - 6) * 16384;
  else if (b < 12) W = Bs + (b - 9) * 16384;
  else if (b < 15) W = Cs + (b - 12) * 16384;
  else if (b == 15) W = gsw;
  else if (b == 16) W = gdw;
  else if (b == 17) W = Ow;
  else if (b == 18) { W = W1 + 128; ldw = 384; }
  else { W = W1 + 256; ldw = 384; }
  short* o = out + (size_t)b * 2048 * 8;
  for (int s = threadIdx.x; s < 2048; s += 512) {
    int ct = s >> 8, ks = (s >> 6) & 3, l = s & 63;
    int row = ct * 16 + (l & 15), k0 = ks * 32 + (l >> 4) * 8;
    *(bf16x8*)&o[s * 8] = cvt8(W + (size_t)row * ldw + k0);
  }
}

// ---------------- embeddings ----------------
__global__ __launch_bounds__(128) void k_node_embed(
    const float* __restrict__ hin, const float* __restrict__ w,
    const float* __restrict__ b, float* __restrict__ h0, int rows) {
  __shared__ float Wt[64 * DF];
  __shared__ float ar[4][64];
  int tid = threadIdx.x;
  for (int i = tid; i < 64 * DF; i += 128) Wt[(i & 63) * DF + (i >> 6)] = w[i];
  float bb = b[tid];
  __syncthreads();
  for (int r0 = blockIdx.x * 4; r0 < rows; r0 += gridDim.x * 4) {
    for (int i = tid; i < 256; i += 128) ar[i >> 6][i & 63] = hin[(size_t)r0 * 64 + i];
    __syncthreads();
    float a0 = bb, a1 = bb, a2 = bb, a3 = bb;
#pragma unroll 8
    for (int k = 0; k < 64; ++k) {
      float wv = Wt[k * DF + tid];
      a0 = fmaf(ar[0][k], wv, a0); a1 = fmaf(ar[1][k], wv, a1);
      a2 = fmaf(ar[2][k], wv, a2); a3 = fmaf(ar[3][k], wv, a3);
    }
    h0[(size_t)r0 * DF + tid] = a0;
    h0[(size_t)(r0 + 1) * DF + tid] = a1;
    h0[(size_t)(r0 + 2) * DF + tid] = a2;
    h0[(size_t)(r0 + 3) * DF + tid] = a3;
    __syncthreads();
  }
}

// permuted edge embed: slot r holds edge eidb[r]
__global__ __launch_bounds__(128) void k_edge_embed(
    const float* __restrict__ ein, const int* __restrict__ eidb,
    const float* __restrict__ w, const float* __restrict__ b,
    unsigned short* __restrict__ e0u, int rows) {
  __shared__ float Wt[16 * DF];
  __shared__ float ar[4][16];
  int tid = threadIdx.x;
  for (int i = tid; i < 16 * DF; i += 128) Wt[(i & 15) * DF + (i >> 4)] = w[i];
  float bb = b[tid];
  __syncthreads();
  for (int r0 = blockIdx.x * 4; r0 < rows; r0 += gridDim.x * 4) {
    if (tid < 64) {
      int e = eidb[r0 + (tid >> 4)];
      ar[tid >> 4][tid & 15] = ein[(size_t)e * 16 + (tid & 15)];
    }
    __syncthreads();
    float a0 = bb, a1 = bb, a2 = bb, a3 = bb;
#pragma unroll
    for (int k = 0; k < 16; ++k) {
      float wv = Wt[k * DF + tid];
      a0 = fmaf(ar[0][k], wv, a0); a1 = fmaf(ar[1][k], wv, a1);
      a2 = fmaf(ar[2][k], wv, a2); a3 = fmaf(ar[3][k], wv, a3);
    }
    e0u[(size_t)r0 * DF + tid] = f2bf(a0);
    e0u[(size_t)(r0 + 1) * DF + tid] = f2bf(a1);
    e0u[(size_t)(r0 + 2) * DF + tid] = f2bf(a2);
    e0u[(size_t)(r0 + 3) * DF + tid] = f2bf(a3);
    __syncthreads();
  }
}

// ---------------- MFMA [rows,128] @ W^T (+bias), frag weights, f32 input ----------------
template <int OUTBF>
__global__ __launch_bounds__(512) void k_gemm_mfma(
    const float* __restrict__ A, const short* __restrict__ Wf,
    const float* __restrict__ bias, void* __restrict__ outv, int rows) {
  __shared__ short Wb[2048 * 8];  // 32 KB
  int tid = threadIdx.x;
  for (int s = tid; s < 2048; s += 512)
    *(bf16x8*)&Wb[s * 8] = *(const bf16x8*)&Wf[(size_t)s * 8];
  __syncthreads();
  float* outf = (float*)outv;
  unsigned short* outb = (unsigned short*)outv;
  int wid = tid >> 6, lane = tid & 63, q = lane >> 4, m = lane & 15;
  int ntiles = (rows + 127) >> 7;
  for (int t = blockIdx.x; t < ntiles; t += gridDim.x) {
    int r0 = t * 128 + wid * 16;
    int rr = r0 + m;
    if (rr >= rows) rr = rows - 1;
    const float* ap = A + (size_t)rr * DF + q * 8;
    bf16x8 a[4];
#pragma unroll
    for (int ks = 0; ks < 4; ++ks) a[ks] = cvt8(ap + 32 * ks);
#pragma unroll
    for (int ct = 0; ct < 8; ++ct) {
      f32x4 acc = {0.f, 0.f, 0.f, 0.f};
#pragma unroll
      for (int ks = 0; ks < 4; ++ks) {
        bf16x8 b = *(const bf16x8*)&Wb[((ct * 4 + ks) * 64 + lane) * 8];
        acc = __builtin_amdgcn_mfma_f32_16x16x32_bf16(a[ks], b, acc, 0, 0, 0);
      }
      int col = ct * 16 + m;
      float bb = bias ? bias[col] : 0.f;
#pragma unroll
      for (int j = 0; j < 4; ++j) {
        int row = r0 + q * 4 + j;
        if (row < rows) {
          if (OUTBF) outb[(size_t)row * DF + col] = f2bf(acc[j] + bb);
          else outf[(size_t)row * DF + col] = acc[j] + bb;
        }
      }
    }
  }
}

// same, bf16 input
__global__ __launch_bounds__(512) void k_gemmb_mfma(
    const unsigned short* __restrict__ A, const short* __restrict__ Wf,
    unsigned short* __restrict__ outb, int rows) {
  __shared__ short Wb[2048 * 8];
  int tid = threadIdx.x;
  for (int s = tid; s < 2048; s += 512)
    *(bf16x8*)&Wb[s * 8] = *(const bf16x8*)&Wf[(size_t)s * 8];
  __syncthreads();
  int wid = tid >> 6, lane = tid & 63, q = lane >> 4, m = lane & 15;
  int ntiles = (rows + 127) >> 7;
  for (int t = blockIdx.x; t < ntiles; t += gridDim.x) {
    int r0 = t * 128 + wid * 16;
    int rr = r0 + m;
    if (rr >= rows) rr = rows - 1;
    const unsigned short* ap = A + (size_t)rr * DF + q * 8;
    bf16x8 a[4];
#pragma unroll
    for (int ks = 0; ks < 4; ++ks) a[ks] = *(const bf16x8*)(ap + 32 * ks);
#pragma unroll
    for (int ct = 0; ct < 8; ++ct) {
      f32x4 acc = {0.f, 0.f, 0.f, 0.f};
#pragma unroll
      for (int ks = 0; ks < 4; ++ks) {
        bf16x8 b = *(const bf16x8*)&Wb[((ct * 4 + ks) * 64 + lane) * 8];
        acc = __builtin_amdgcn_mfma_f32_16x16x32_bf16(a[ks], b, acc, 0, 0, 0);
      }
      int col = ct * 16 + m;
#pragma unroll
      for (int j = 0; j < 4; ++j) {
        int row = r0 + q * 4 + j;
        if (row < rows) outb[(size_t)row * DF + col] = f2bf(acc[j]);
      }
    }
  }
}

// ---------------- fused 4-output node GEMM (V,U,B,C) ----------------
__global__ __launch_bounds__(512) void k_gemm4_mfma(
    const float* __restrict__ h0, const short* __restrict__ Vf,
    const short* __restrict__ Uf, const short* __restrict__ Bf,
    const short* __restrict__ Cf, unsigned short* __restrict__ hVb,
    float* __restrict__ hU, unsigned short* __restrict__ hBb,
    unsigned short* __restrict__ hCb, int rows) {
  __shared__ short Wl[4 * 2048 * 8];  // 128 KB
  int tid = threadIdx.x;
  for (int s = tid; s < 2048; s += 512) {
    *(bf16x8*)&Wl[(size_t)s * 8] = *(const bf16x8*)&Vf[(size_t)s * 8];
    *(bf16x8*)&Wl[(size_t)(2048 + s) * 8] = *(const bf16x8*)&Uf[(size_t)s * 8];
    *(bf16x8*)&Wl[(size_t)(4096 + s) * 8] = *(const bf16x8*)&Bf[(size_t)s * 8];
    *(bf16x8*)&Wl[(size_t)(6144 + s) * 8] = *(const bf16x8*)&Cf[(size_t)s * 8];
  }
  __syncthreads();
  int wid = tid >> 6, lane = tid & 63, q = lane >> 4, m = lane & 15;
  int ntiles = (rows + 127) >> 7;
  for (int t = blockIdx.x; t < ntiles; t += gridDim.x) {
    int r0 = t * 128 + wid * 16;
    int rr = r0 + m;
    if (rr >= rows) rr = rows - 1;
    const float* ap = h0 + (size_t)rr * DF + q * 8;
    bf16x8 a[4];
#pragma unroll
    for (int ks = 0; ks < 4; ++ks) a[ks] = cvt8(ap + 32 * ks);
#pragma unroll
    for (int w = 0; w < 4; ++w) {
#pragma unroll
      for (int ct = 0; ct < 8; ++ct) {
        f32x4 acc = {0.f, 0.f, 0.f, 0.f};
#pragma unroll
        for (int ks = 0; ks < 4; ++ks) {
          bf16x8 b = *(const bf16x8*)&Wl[((w * 2048) + (ct * 4 + ks) * 64 + lane) * 8];
          acc = __builtin_amdgcn_mfma_f32_16x16x32_bf16(a[ks], b, acc, 0, 0, 0);
        }
        int col = ct * 16 + m;
#pragma unroll
        for (int j = 0; j < 4; ++j) {
          int row = r0 + q * 4 + j;
          if (row < rows) {
            if (w == 1) hU[(size_t)row * DF + col] = acc[j];
            else {
              unsigned short v = f2bf(acc[j]);
              unsigned short* o = (w == 0) ? hVb : ((w == 2) ? hBb : hCb);
              o[(size_t)row * DF + col] = v;
            }
          }
        }
      }
    }
  }
}

// ======== barrier-free swapped edge passes (mfma(W, e): lane owns ONE edge) ========
#define EDGE_MFMA_BODY                                                                 \
  const unsigned short* ep = e0u + (size_t)ec * DF + q * 8;                            \
  bf16x8 bv0 = *(const bf16x8*)(ep);                                                   \
  bf16x8 bv1 = *(const bf16x8*)(ep + 32);                                              \
  bf16x8 bv2 = *(const bf16x8*)(ep + 64);                                              \
  bf16x8 bv3 = *(const bf16x8*)(ep + 96);                                              \
  f32x4 c0 = {0.f, 0.f, 0.f, 0.f}, c1 = c0, c2 = c0, c3 = c0;                          \
  f32x4 c4 = c0, c5 = c0, c6 = c0, c7 = c0;                                            \
  _Pragma("unroll") for (int ks = 0; ks < 4; ++ks) {                                   \
    bf16x8 bv = (ks == 0) ? bv0 : (ks == 1) ? bv1 : (ks == 2) ? bv2 : bv3;             \
    c0 = __builtin_amdgcn_mfma_f32_16x16x32_bf16(*(const bf16x8*)&Wb[((0 * 4 + ks) * 64 + lane) * 8], bv, c0, 0, 0, 0); \
    c1 = __builtin_amdgcn_mfma_f32_16x16x32_bf16(*(const bf16x8*)&Wb[((1 * 4 + ks) * 64 + lane) * 8], bv, c1, 0, 0, 0); \
    c2 = __builtin_amdgcn_mfma_f32_16x16x32_bf16(*(const bf16x8*)&Wb[((2 * 4 + ks) * 64 + lane) * 8], bv, c2, 0, 0, 0); \
    c3 = __builtin_amdgcn_mfma_f32_16x16x32_bf16(*(const bf16x8*)&Wb[((3 * 4 + ks) * 64 + lane) * 8], bv, c3, 0, 0, 0); \
    c4 = __builtin_amdgcn_mfma_f32_16x16x32_bf16(*(const bf16x8*)&Wb[((4 * 4 + ks) * 64 + lane) * 8], bv, c4, 0, 0, 0); \
    c5 = __builtin_amdgcn_mfma_f32_16x16x32_bf16(*(const bf16x8*)&Wb[((5 * 4 + ks) * 64 + lane) * 8], bv, c5, 0, 0, 0); \
    c6 = __builtin_amdgcn_mfma_f32_16x16x32_bf16(*(const bf16x8*)&Wb[((6 * 4 + ks) * 64 + lane) * 8], bv, c6, 0, 0, 0); \
    c7 = __builtin_amdgcn_mfma_f32_16x16x32_bf16(*(const bf16x8*)&Wb[((7 * 4 + ks) * 64 + lane) * 8], bv, c7, 0, 0, 0); \
  }

// stats pass
__global__ __launch_bounds__(512) void k_edge_xs(
    const unsigned short* __restrict__ e0u, const short* __restrict__ Af,
    const unsigned short* __restrict__ hBb, const unsigned short* __restrict__ hCb,
    const int* __restrict__ srcP, const int* __restrict__ dstP,
    float* __restrict__ stat, int Eg) {
  __shared__ short Wb[2048 * 8];  // 32 KB
  __shared__ float ls[256];
  int tid = threadIdx.x;
  for (int s = tid; s < 2048; s += 512)
    *(bf16x8*)&Wb[s * 8] = *(const bf16x8*)&Af[(size_t)s * 8];
  if (tid < 256) ls[tid] = 0.f;
  int wid = tid >> 6, lane = tid & 63, q = lane >> 4, m = lane & 15;
  int g = blockIdx.x & 7, sub = blockIdx.x >> 3, nsub = gridDim.x >> 3;
  int gbase = g * Eg, gend = gbase + Eg;
  int tpg = (Eg + 127) >> 7;
  float ps[32], pq[32];
#pragma unroll
  for (int i = 0; i < 32; ++i) { ps[i] = 0.f; pq[i] = 0.f; }
  __syncthreads();
  for (int t = sub; t < tpg; t += nsub) {
    int r0 = gbase + t * 128 + wid * 16;
    int edge = r0 + m;
    bool ok = edge < gend;
    int ec = ok ? edge : gend - 1;
    EDGE_MFMA_BODY
    if (ok) {
      int sidx = srcP[ec], didx = dstP[ec];
      const unsigned short* pb = hBb + (size_t)didx * DF + q * 4;
      const unsigned short* pc = hCb + (size_t)sidx * DF + q * 4;
#pragma unroll
      for (int ct = 0; ct < 8; ++ct) {
        f32x4 cc = (ct == 0) ? c0 : (ct == 1) ? c1 : (ct == 2) ? c2 : (ct == 3) ? c3
                   : (ct == 4) ? c4 : (ct == 5) ? c5 : (ct == 6) ? c6 : c7;
        ushort4 hb = *(const ushort4*)(pb + ct * 16);
        ushort4 hc = *(const ushort4*)(pc + ct * 16);
        float x0 = cc[0] + bf2f(hb.x) + bf2f(hc.x);
        float x1 = cc[1] + bf2f(hb.y) + bf2f(hc.y);
        float x2 = cc[2] + bf2f(hb.z) + bf2f(hc.z);
        float x3 = cc[3] + bf2f(hb.w) + bf2f(hc.w);
        ps[ct * 4 + 0] += x0; pq[ct * 4 + 0] += x0 * x0;
        ps[ct * 4 + 1] += x1; pq[ct * 4 + 1] += x1 * x1;
        ps[ct * 4 + 2] += x2; pq[ct * 4 + 2] += x2 * x2;
        ps[ct * 4 + 3] += x3; pq[ct * 4 + 3] += x3 * x3;
      }
    }
  }
#pragma unroll
  for (int i = 0; i < 32; ++i) {
    float s = ps[i], sq = pq[i];
    s += __shfl_xor(s, 1, 64); sq += __shfl_xor(sq, 1, 64);
    s += __shfl_xor(s, 2, 64); sq += __shfl_xor(sq, 2, 64);
    s += __shfl_xor(s, 4, 64); sq += __shfl_xor(sq, 4, 64);
    s += __shfl_xor(s, 8, 64); sq += __shfl_xor(sq, 8, 64);
    if (m == 0) {
      int feat = (i >> 2) * 16 + q * 4 + (i & 3);
      atomicAdd(&ls[feat], s);
      atomicAdd(&ls[128 + feat], sq);
    }
  }
  __syncthreads();
  if (tid < 128) {
    atomicAdd(&stat[512 + tid], ls[tid]);
    atomicAdd(&stat[640 + tid], ls[128 + tid]);
  }
}

// apply pass
__global__ __launch_bounds__(512) void k_edge_xa(
    unsigned short* __restrict__ e0u, const short* __restrict__ Af,
    const unsigned short* __restrict__ hBb, const unsigned short* __restrict__ hCb,
    const int* __restrict__ srcP, const int* __restrict__ dstP,
    const float* __restrict__ stat, int Eg) {
  __shared__ short Wb[2048 * 8];  // 32 KB
  int tid = threadIdx.x;
  for (int s = tid; s < 2048; s += 512)
    *(bf16x8*)&Wb[s * 8] = *(const bf16x8*)&Af[(size_t)s * 8];
  int wid = tid >> 6, lane = tid & 63, q = lane >> 4, m = lane & 15;
  float mm[32], iv[32];
#pragma unroll
  for (int ct = 0; ct < 8; ++ct)
#pragma unroll
    for (int j = 0; j < 4; ++j) {
      int f = ct * 16 + q * 4 + j;
      mm[ct * 4 + j] = stat[768 + f];
      iv[ct * 4 + j] = stat[896 + f];
    }
  int g = blockIdx.x & 7, sub = blockIdx.x >> 3, nsub = gridDim.x >> 3;
  int gbase = g * Eg, gend = gbase + Eg;
  int tpg = (Eg + 127) >> 7;
  __syncthreads();
  for (int t = sub; t < tpg; t += nsub) {
    int r0 = gbase + t * 128 + wid * 16;
    int edge = r0 + m;
    bool ok = edge < gend;
    int ec = ok ? edge : gend - 1;
    EDGE_MFMA_BODY
    if (ok) {
      int sidx = srcP[ec], didx = dstP[ec];
      const unsigned short* pb = hBb + (size_t)didx * DF + q * 4;
      const unsigned short* pc = hCb + (size_t)sidx * DF + q * 4;
      unsigned short* pe = e0u + (size_t)ec * DF + q * 4;
#pragma unroll
      for (int ct = 0; ct < 8; ++ct) {
        f32x4 cc = (ct == 0) ? c0 : (ct == 1) ? c1 : (ct == 2) ? c2 : (ct == 3) ? c3
                   : (ct == 4) ? c4 : (ct == 5) ? c5 : (ct == 6) ? c6 : c7;
        ushort4 hb = *(const ushort4*)(pb + ct * 16);
        ushort4 hc = *(const ushort4*)(pc + ct * 16);
        ushort4 eo = *(const ushort4*)(pe + ct * 16);
        float x0 = cc[0] + bf2f(hb.x) + bf2f(hc.x);
        float x1 = cc[1] + bf2f(hb.y) + bf2f(hc.y);
        float x2 = cc[2] + bf2f(hb.z) + bf2f(hc.z);
        float x3 = cc[3] + bf2f(hb.w) + bf2f(hc.w);
        ushort4 nv;
        nv.x = f2bf(bf2f(eo.x) + fmaxf((x0 - mm[ct * 4 + 0]) * iv[ct * 4 + 0], 0.f));
        nv.y = f2bf(bf2f(eo.y) + fmaxf((x1 - mm[ct * 4 + 1]) * iv[ct * 4 + 1], 0.f));
        nv.z = f2bf(bf2f(eo.z) + fmaxf((x2 - mm[ct * 4 + 2]) * iv[ct * 4 + 2], 0.f));
        nv.w = f2bf(bf2f(eo.w) + fmaxf((x3 - mm[ct * 4 + 3]) * iv[ct * 4 + 3], 0.f));
        *(ushort4*)(pe + ct * 16) = nv;
      }
    }
  }
}

// ---------------- node-major segment max (CSR-streamed e0u) ----------------
__global__ __launch_bounds__(256) void k_node_agg(
    float* __restrict__ hU, const unsigned short* __restrict__ hVb,
    const unsigned short* __restrict__ e0u, const int* __restrict__ srcP,
    const unsigned* __restrict__ rowptr, float* __restrict__ stat, int Ngr) {
  __shared__ float sr[4][256];
  int tid = threadIdx.x, wid = tid >> 6, lane = tid & 63;
  int g = blockIdx.x & 7, sub = blockIdx.x >> 3, nsub = gridDim.x >> 3;
  float ps0 = 0.f, ps1 = 0.f, pq0 = 0.f, pq1 = 0.f;
  for (int nn = sub * 4 + wid; nn < Ngr; nn += nsub * 4) {
    int n = g * Ngr + nn;
    unsigned r0 = rowptr[n], r1 = rowptr[n + 1];
    float m0 = -3.4e38f, m1 = -3.4e38f;
    for (unsigned rc = r0; rc < r1; rc += 64) {
      int batch = (int)min(64u, r1 - rc);
      int myS = srcP[rc + ((lane < batch) ? lane : 0)];
      int j = 0;
      for (; j + 4 <= batch; j += 4) {
        int s0 = __shfl(myS, j, 64), s1 = __shfl(myS, j + 1, 64);
        int s2 = __shfl(myS, j + 2, 64), s3 = __shfl(myS, j + 3, 64);
        unsigned h0v = *(const unsigned*)&hVb[(size_t)s0 * DF + 2 * lane];
        unsigned h1v = *(const unsigned*)&hVb[(size_t)s1 * DF + 2 * lane];
        unsigned h2v = *(const unsigned*)&hVb[(size_t)s2 * DF + 2 * lane];
        unsigned h3v = *(const unsigned*)&hVb[(size_t)s3 * DF + 2 * lane];
        unsigned v0 = *(const unsigned*)&e0u[(size_t)(rc + j) * DF + 2 * lane];
        unsigned v1 = *(const unsigned*)&e0u[(size_t)(rc + j + 1) * DF + 2 * lane];
        unsigned v2 = *(const unsigned*)&e0u[(size_t)(rc + j + 2) * DF + 2 * lane];
        unsigned v3 = *(const unsigned*)&e0u[(size_t)(rc + j + 3) * DF + 2 * lane];
        agg_max(h0v, v0, m0, m1);
        agg_max(h1v, v1, m0, m1);
        agg_max(h2v, v2, m0, m1);
        agg_max(h3v, v3, m0, m1);
      }
      for (; j < batch; ++j) {
        int s = __shfl(myS, j, 64);
        unsigned hv = *(const unsigned*)&hVb[(size_t)s * DF + 2 * lane];
        unsigned ev = *(const unsigned*)&e0u[(size_t)(rc + j) * DF + 2 * lane];
        agg_max(hv, ev, m0, m1);
      }
    }
    if (r1 == r0) { m0 = 0.f; m1 = 0.f; }
    size_t idx = (size_t)n * DF + 2 * lane;
    float2 hu = *(float2*)&hU[idx];
    float t0 = hu.x + m0, t1 = hu.y + m1;
    hu.x = t0; hu.y = t1;
    *(float2*)&hU[idx] = hu;
    ps0 += t0; ps1 += t1;
    pq0 += t0 * t0; pq1 += t1 * t1;
  }
  sr[0][tid] = ps0; sr[1][tid] = ps1; sr[2][tid] = pq0; sr[3][tid] = pq1;
  __syncthreads();
  if (tid < 64) {
    float a0 = 0.f, a1 = 0.f, b0 = 0.f, b1 = 0.f;
#pragma unroll
    for (int w = 0; w < 4; ++w) {
      a0 += sr[0][w * 64 + tid]; a1 += sr[1][w * 64 + tid];
      b0 += sr[2][w * 64 + tid]; b1 += sr[3][w * 64 + tid];
    }
    atomicAdd(&stat[2 * tid], a0);
    atomicAdd(&stat[2 * tid + 1], a1);
    atomicAdd(&stat[128 + 2 * tid], b0);
    atomicAdd(&stat[128 + 2 * tid + 1], b1);
  }
}

// finalize BN stats
__global__ void k_bn_finalize(float* __restrict__ stat, float nN, float nE) {
  int tid = threadIdx.x;
  if (tid < 128) {
    float mean = stat[tid] / nN;
    float var = stat[128 + tid] / nN - mean * mean;
    stat[256 + tid] = mean;
    stat[384 + tid] = rsqrtf(fmaxf(var, 0.f) + 1e-5f);
  } else {
    int d = tid - 128;
    float mean = stat[512 + d] / nE;
    float var = stat[640 + d] / nE - mean * mean;
    stat[768 + d] = mean;
    stat[896 + d] = rsqrtf(fmaxf(var, 0.f) + 1e-5f);
  }
}

__global__ __launch_bounds__(256) void k_node_update(
    float* __restrict__ h0, const float* __restrict__ hU,
    const float* __restrict__ stat, long long total) {
  long long i = (long long)blockIdx.x * blockDim.x + threadIdx.x;
  long long st = (long long)gridDim.x * blockDim.x;
  for (; i < total; i += st) {
    int d = (int)(i & 127);
    float t = (hU[i] - stat[256 + d]) * stat[384 + d];
    h0[i] += fmaxf(t, 0.f);
  }
}

// ---------------- GATv2 score (permuted edge-major) ----------------
__global__ __launch_bounds__(256) void k_gat_score(
    const unsigned short* __restrict__ fsb, const unsigned short* __restrict__ fdb,
    const int* __restrict__ srcP, const int* __restrict__ dstP,
    const float* __restrict__ attn, float* __restrict__ score, int E) {
  long long i = (long long)blockIdx.x * blockDim.x + threadIdx.x;
  long long st = (long long)gridDim.x * blockDim.x;
  long long total = (long long)E * 8;
  for (; i < total; i += st) {
    int e = (int)(i >> 3), mh = (int)(i & 7);
    int s = srcP[e], dn = dstP[e];
    const unsigned short* ps = fsb + (size_t)s * DF + mh * 16;
    const unsigned short* pd = fdb + (size_t)dn * DF + mh * 16;
    const float* pa = attn + mh * 16;
    bf16x8 s0 = *(const bf16x8*)ps;
    bf16x8 s1 = *(const bf16x8*)(ps + 8);
    bf16x8 d0 = *(const bf16x8*)pd;
    bf16x8 d1 = *(const bf16x8*)(pd + 8);
    float acc = 0.f;
#pragma unroll
    for (int kk = 0; kk < 8; ++kk) {
      float z = bf2f((unsigned short)s0[kk]) + bf2f((unsigned short)d0[kk]);
      z = (z > 0.f) ? z : 0.2f * z;
      acc = fmaf(z, pa[kk], acc);
      float z2 = bf2f((unsigned short)s1[kk]) + bf2f((unsigned short)d1[kk]);
      z2 = (z2 > 0.f) ? z2 : 0.2f * z2;
      acc = fmaf(z2, pa[kk + 8], acc);
    }
    score[i] = acc;
  }
}

// ---------------- GATv2 node reduction (streamed scores) ----------------
__global__ __launch_bounds__(256) void k_gat_node(
    const float* __restrict__ score, const unsigned short* __restrict__ fsb,
    const int* __restrict__ srcP, const unsigned* __restrict__ rowptr,
    float* __restrict__ rst, int Ngr) {
  int tid = threadIdx.x, wid = tid >> 6, lane = tid & 63;
  int g = blockIdx.x & 7, sub = blockIdx.x >> 3, nsub = gridDim.x >> 3;
  int head = lane >> 3, slot = lane & 7;
  for (int nn = sub * 4 + wid; nn < Ngr; nn += nsub * 4) {
    int n = g * Ngr + nn;
    unsigned r0 = rowptr[n], r1 = rowptr[n + 1];
    float hm = -3.4e38f;
    for (unsigned r = r0 + slot; r < r1; r += 8)
      hm = fmaxf(hm, score[(size_t)r * 8 + head]);
#pragma unroll
    for (int mk = 1; mk < 8; mk <<= 1) hm = fmaxf(hm, __shfl_xor(hm, mk, 64));
    float dn = 0.f;
    for (unsigned r = r0 + slot; r < r1; r += 8)
      dn += __expf(score[(size_t)r * 8 + head] - hm);
#pragma unroll
    for (int mk = 1; mk < 8; mk <<= 1) dn += __shfl_xor(dn, mk, 64);
    float inv = (r1 > r0) ? 1.f / dn : 0.f;
    float a0 = 0.f, a1 = 0.f;
    for (unsigned rc = r0; rc < r1; rc += 64) {
      int batch = (int)min(64u, r1 - rc);
      int myS = srcP[rc + ((lane < batch) ? lane : 0)];
      int j = 0;
      for (; j + 4 <= batch; j += 4) {
        int s0 = __shfl(myS, j, 64), s1 = __shfl(myS, j + 1, 64);
        int s2 = __shfl(myS, j + 2, 64), s3 = __shfl(myS, j + 3, 64);
        float sc0 = score[(size_t)(rc + j) * 8 + head];
        float sc1 = score[(size_t)(rc + j + 1) * 8 + head];
        float sc2 = score[(size_t)(rc + j + 2) * 8 + head];
        float sc3 = score[(size_t)(rc + j + 3) * 8 + head];
        unsigned f0 = *(const unsigned*)&fsb[(size_t)s0 * DF + 2 * lane];
        unsigned f1 = *(const unsigned*)&fsb[(size_t)s1 * DF + 2 * lane];
        unsigned f2 = *(const unsigned*)&fsb[(size_t)s2 * DF + 2 * lane];
        unsigned f3 = *(const unsigned*)&fsb[(size_t)s3 * DF + 2 * lane];
        float w0 = __expf(sc0 - hm) * inv, w1 = __expf(sc1 - hm) * inv;
        float w2 = __expf(sc2 - hm) * inv, w3 = __expf(sc3 - hm) * inv;
        a0 = fmaf(w0, bflo(f0), a0); a1 = fmaf(w0, bfhi(f0), a1);
        a0 = fmaf(w1, bflo(f1), a0); a1 = fmaf(w1, bfhi(f1), a1);
        a0 = fmaf(w2, bflo(f2), a0); a1 = fmaf(w2, bfhi(f2), a1);
        a0 = fmaf(w3, bflo(f3), a0); a1 = fmaf(w3, bfhi(f3), a1);
      }
      for (; j < batch; ++j) {
        int s = __shfl(myS, j, 64);
        float w = __expf(score[(size_t)(rc + j) * 8 + head] - hm) * inv;
        unsigned fv = *(const unsigned*)&fsb[(size_t)s * DF + 2 * lane];
        a0 = fmaf(w, bflo(fv), a0);
        a1 = fmaf(w, bfhi(fv), a1);
      }
    }
    float2 o;
    o.x = a0; o.y = a1;
    *(float2*)&rst[(size_t)n * DF + 2 * lane] = o;
  }
}

// bias2 = O_b + gat_bias @ O_w^T
__global__ void k_bias2(const float* __restrict__ gat_bias,
                        const float* __restrict__ O_w,
                        const float* __restrict__ O_b, float* __restrict__ bias2) {
  int d = threadIdx.x;
  float acc = O_b[d];
  for (int k = 0; k < DF; ++k) acc = fmaf(gat_bias[k], O_w[(size_t)d * DF + k], acc);
  bias2[d] = acc;
}

// ---------------- readout ----------------
__global__ __launch_bounds__(128) void k_moy(
    const unsigned short* __restrict__ h2b, const int* __restrict__ ng,
    float* __restrict__ moy, float* __restrict__ cnt, int rows) {
  int tid = threadIdx.x;
  int per = (rows + gridDim.x - 1) / gridDim.x;
  int n0 = blockIdx.x * per;
  int n1 = min(rows, n0 + per);
  if (n0 >= n1) return;
  int cur = ng[n0];
  float acc = 0.f; int c = 0;
  for (int n = n0; n < n1; ++n) {
    int g = ng[n];
    if (g != cur) {
      atomicAdd(&moy[cur * DF + tid], acc);
      if (tid == 0) atomicAdd(&cnt[cur], (float)c);
      acc = 0.f; c = 0; cur = g;
    }
    acc += bf2f(h2b[(size_t)n * DF + tid]);
    ++c;
  }
  atomicAdd(&moy[cur * DF + tid], acc);
  if (tid == 0) atomicAdd(&cnt[cur], (float)c);
}

// P0[g] = W1[:,0:128] @ (moy_sum[g]/cnt[g]) + W1_b
__global__ void k_p0(const float* __restrict__ W1, const float* __restrict__ W1b_,
                     const float* __restrict__ moy, const float* __restrict__ cnt,
                     float* __restrict__ P0) {
  int g = blockIdx.x, d = threadIdx.x;
  float inv = 1.f / cnt[g];
  float acc = W1b_[d];
  for (int k = 0; k < DF; ++k) acc = fmaf(W1[(size_t)d * 384 + k], moy[g * DF + k] * inv, acc);
  P0[g * DF + d] = acc;
}

// ---------------- CSR head (permuted; out scatter via eidb) ----------------
__global__ __launch_bounds__(256) void k_head(
    const unsigned short* __restrict__ P1b, const unsigned short* __restrict__ P2b,
    const float* __restrict__ P0, const int* __restrict__ srcP,
    const unsigned* __restrict__ rowptr, const int* __restrict__ eidb,
    const float* __restrict__ W2, const float* __restrict__ W2b,
    float* __restrict__ out, int Ngr) {
  int tid = threadIdx.x, wid = tid >> 6, lane = tid & 63;
  int g = blockIdx.x & 7, sub = blockIdx.x >> 3, nsub = gridDim.x >> 3;
  float w2b = W2b[0];
  float w20 = W2[2 * lane], w21 = W2[2 * lane + 1];
  float b0 = P0[g * DF + 2 * lane], b1v = P0[g * DF + 2 * lane + 1];
  for (int nn = sub * 4 + wid; nn < Ngr; nn += nsub * 4) {
    int n = g * Ngr + nn;
    unsigned r0 = rowptr[n], r1 = rowptr[n + 1];
    if (r1 == r0) continue;
    unsigned p2 = *(const unsigned*)&P2b[(size_t)n * DF + 2 * lane];
    float base0 = b0 + bflo(p2);
    float base1 = b1v + bfhi(p2);
    for (unsigned rc = r0; rc < r1; rc += 64) {
      int cnt2 = (int)min(64u, r1 - rc);
      int myE = eidb[rc + ((lane < cnt2) ? lane : 0)];
      int myS = srcP[rc + ((lane < cnt2) ? lane : 0)];
      int j = 0;
      for (; j + 4 <= cnt2; j += 4) {
        int e0 = __shfl(myE, j, 64), e1 = __shfl(myE, j + 1, 64);
        int e2 = __shfl(myE, j + 2, 64), e3 = __shfl(myE, j + 3, 64);
        int s0 = __shfl(myS, j, 64), s1 = __shfl(myS, j + 1, 64);
        int s2 = __shfl(myS, j + 2, 64), s3 = __shfl(myS, j + 3, 64);
        unsigned u0 = *(const unsigned*)&P1b[(size_t)s0 * DF + 2 * lane];
        unsigned u1 = *(const unsigned*)&P1b[(size_t)s1 * DF + 2 * lane];
        unsigned u2 = *(const unsigned*)&P1b[(size_t)s2 * DF + 2 * lane];
        unsigned u3 = *(const unsigned*)&P1b[(size_t)s3 * DF + 2 * lane];
        float v0 = fmaxf(base0 + bflo(u0), 0.f) * w20 + fmaxf(base1 + bfhi(u0), 0.f) * w21;
        float v1 = fmaxf(base0 + bflo(u1), 0.f) * w20 + fmaxf(base1 + bfhi(u1), 0.f) * w21;
        float v2 = fmaxf(base0 + bflo(u2), 0.f) * w20 + fmaxf(base1 + bfhi(u2), 0.f) * w21;
        float v3 = fmaxf(base0 + bflo(u3), 0.f) * w20 + fmaxf(base1 + bfhi(u3), 0.f) * w21;
#pragma unroll
        for (int mk = 1; mk < 64; mk <<= 1) {
          v0 += __shfl_xor(v0, mk, 64);
          v1 += __shfl_xor(v1, mk, 64);
          v2 += __shfl_xor(v2, mk, 64);
          v3 += __shfl_xor(v3, mk, 64);
        }
        if (lane == 0) {
          out[e0] = sigm(v0 + w2b);
          out[e1] = sigm(v1 + w2b);
          out[e2] = sigm(v2 + w2b);
          out[e3] = sigm(v3 + w2b);
        }
      }
      for (; j < cnt2; ++j) {
        int e = __shfl(myE, j, 64);
        int s = __shfl(myS, j, 64);
        unsigned p1 = *(const unsigned*)&P1b[(size_t)s * DF + 2 * lane];
        float v = fmaxf(base0 + bflo(p1), 0.f) * w20 + fmaxf(base1 + bfhi(p1), 0.f) * w21;
#pragma unroll
        for (int mk = 1; mk < 64; mk <<= 1) v += __shfl_xor(v, mk, 64);
        if (lane == 0) out[e] = sigm(v + w2b);
      }
    }
  }
}

extern "C" void kernel_launch(void* const* d_in, const int* in_sizes, int n_in,
                              void* d_out, int out_size, void* d_ws, size_t ws_size,
                              hipStream_t stream) {
  const float* h_in = (const float*)d_in[0];
  const float* e_in = (const float*)d_in[1];
  const int* src = (const int*)d_in[2];
  const int* dst = (const int*)d_in[3];
  const int* node_graph = (const int*)d_in[4];
  const float* emb_n_w = (const float*)d_in[6];
  const float* emb_n_b = (const float*)d_in[7];
  const float* emb_e_w = (const float*)d_in[8];
  const float* emb_e_b = (const float*)d_in[9];
  const float* Us = (const float*)d_in[10];
  const float* Vs = (const float*)d_in[11];
  const float* As = (const float*)d_in[12];
  const float* Bs = (const float*)d_in[13];
  const float* Cs = (const float*)d_in[14];
  const float* gat_src_w = (const float*)d_in[15];
  const float* gat_src_b = (const float*)d_in[16];
  const float* gat_dst_w = (const float*)d_in[17];
  const float* gat_dst_b = (const float*)d_in[18];
  const float* gat_attn = (const float*)d_in[19];
  const float* gat_bias = (const float*)d_in[20];
  const float* O_w = (const float*)d_in[21];
  const float* O_b = (const float*)d_in[22];
  const float* W1_w = (const float*)d_in[23];
  const float* W1_b = (const float*)d_in[24];
  const float* W2_w = (const float*)d_in[25];
  const float* W2_b = (const float*)d_in[26];
  float* out = (float*)d_out;

  const int N = in_sizes[0] / 64;   // 30000
  const int E = in_sizes[1] / 16;   // 360000
  const int Eg = E / NGRAPH;        // 45000
  const int Ngr = N / NGRAPH;       // 3750

  auto rnd = [](size_t b) { return (b + 255) & ~(size_t)255; };
  const size_t sz_e0 = rnd((size_t)E * DF * 2);
  const size_t sz_node = rnd((size_t)N * DF * 4);
  const size_t sz_nodeb = rnd((size_t)N * DF * 2);
  const size_t sz_score = rnd((size_t)E * 8 * 4);
  const size_t sz_wfrag = rnd(20 * 2048 * 8 * 2);
  const size_t sz_rp = rnd((size_t)(N + 1) * 4);
  const size_t sz_eid = rnd((size_t)E * 4);
  const size_t sz_misc = rnd(4096 * 4);
  const size_t needed = sz_e0 + 3 * sz_node + 4 * sz_nodeb + sz_score + sz_wfrag +
                        3 * sz_rp + 3 * sz_eid + sz_misc;
  if (ws_size < needed) {
    k_fill_u32<<<256, 256, 0, stream>>>((unsigned*)out, 0xBF800000u, (long long)out_size);
    return;
  }

  char* wp = (char*)d_ws;
  auto alloc = [&](size_t bytes) { void* p = wp; wp += bytes; return p; };
  unsigned short* e0u = (unsigned short*)alloc(sz_e0);
  float* h0 = (float*)alloc(sz_node);
  float* hU = (float*)alloc(sz_node);
  float* rst = (float*)alloc(sz_node);
  unsigned short* hVb = (unsigned short*)alloc(sz_nodeb);
  unsigned short* hBb = (unsigned short*)alloc(sz_nodeb);
  unsigned short* hCb = (unsigned short*)alloc(sz_nodeb);
  unsigned short* h2b = (unsigned short*)alloc(sz_nodeb);
  float* score = (float*)alloc(sz_score);
  short* wfrag = (short*)alloc(sz_wfrag);
  unsigned* rowptr = (unsigned*)alloc(sz_rp);
  unsigned* cursor = (unsigned*)alloc(sz_rp);
  unsigned* deg = (unsigned*)alloc(sz_rp);
  int* eidb = (int*)alloc(sz_eid);
  int* srcP = (int*)alloc(sz_eid);
  int* dstP = (int*)alloc(sz_eid);
  float* misc = (float*)alloc(sz_misc);
  float* stat = misc;                                     // [0,1024)
  float* bias2 = misc + 1024;                             // [1024,1152)
  float* moy = misc + 1152;                               // [1152,2176)
  float* cnt = misc + 2176;                               // [2176,2184)
  float* P0 = misc + 2304;                                // [2304,3328)
  unsigned short* P1b = e0u;  // alias: e0u dead after last layer
  unsigned short* P2b = e0u + (size_t)N * DF;

  auto WF = [&](int idx) { return wfrag + (size_t)idx * 2048 * 8; };

  // CSR build + permuted indices
  k_fill_u32<<<64, 256, 0, stream>>>(deg, 0u, N);
  k_deg<<<512, 256, 0, stream>>>(dst, deg, E);
  k_scan<<<1, 1024, 0, stream>>>(deg, rowptr, cursor, N);
  k_scatter<<<512, 256, 0, stream>>>(dst, cursor, eidb, E);
  k_permidx<<<512, 256, 0, stream>>>(eidb, src, dst, srcP, dstP, E);

  k_wconv<<<20, 512, 0, stream>>>(Us, Vs, As, Bs, Cs, gat_src_w, gat_dst_w, O_w,
                                  W1_w, wfrag);

  const int gN = (N + 127) / 128;
  k_node_embed<<<2048, 128, 0, stream>>>(h_in, emb_n_w, emb_n_b, h0, N);
  k_edge_embed<<<4096, 128, 0, stream>>>(e_in, eidb, emb_e_w, emb_e_b, e0u, E);

  for (int l = 0; l < 3; ++l) {
    k_gemm4_mfma<<<gN, 512, 0, stream>>>(h0, WF(3 + l), WF(l), WF(9 + l), WF(12 + l),
                                         hVb, hU, hBb, hCb, N);
    k_fill_u32<<<4, 256, 0, stream>>>((unsigned*)stat, 0u, 1024);
    k_node_agg<<<2048, 256, 0, stream>>>(hU, hVb, e0u, srcP, rowptr, stat, Ngr);
    k_edge_xs<<<1024, 512, 0, stream>>>(e0u, WF(6 + l), hBb, hCb, srcP, dstP, stat, Eg);
    k_bn_finalize<<<1, 256, 0, stream>>>(stat, (float)N, (float)E);
    k_node_update<<<2048, 256, 0, stream>>>(h0, hU, stat, (long long)N * DF);
    k_edge_xa<<<1024, 512, 0, stream>>>(e0u, WF(6 + l), hBb, hCb, srcP, dstP, stat, Eg);
  }

  // GATv2: fs -> hVb, fd -> hBb
  k_gemm_mfma<1><<<gN, 512, 0, stream>>>(h0, WF(15), gat_src_b, hVb, N);
  k_gemm_mfma<1><<<gN, 512, 0, stream>>>(h0, WF(16), gat_dst_b, hBb, N);
  k_gat_score<<<2048, 256, 0, stream>>>(hVb, hBb, srcP, dstP, gat_attn, score, E);
  k_gat_node<<<2048, 256, 0, stream>>>(score, hVb, srcP, rowptr, rst, Ngr);
  k_bias2<<<1, 128, 0, stream>>>(gat_bias, O_w, O_b, bias2);
  k_gemm_mfma<1><<<gN, 512, 0, stream>>>(rst, WF(17), bias2, h2b, N);  // h2

  // readout + decomposed head
  k_fill_u32<<<2, 256, 0, stream>>>((unsigned*)moy, 0u, 1032);
  k_moy<<<128, 128, 0, stream>>>(h2b, node_graph, moy, cnt, N);
  k_p0<<<8, 128, 0, stream>>>(W1_w, W1_b, moy, cnt, P0);
  k_gemmb_mfma<<<gN, 512, 0, stream>>>(h2b, WF(18), P1b, N);
  k_gemmb_mfma<<<gN, 512, 0, stream>>>(h2b, WF(19), P2b, N);
  k_head<<<2048, 256, 0, stream>>>(P1b, P2b, P0, srcP, rowptr, eidb, W2_w, W2_b,
                                   out, Ngr);
}

// Round 16
// 1267.523 us; speedup vs baseline: 1.4163x; 1.0947x over previous
//
#include <hip/hip_runtime.h>

#define DF 128
#define NGRAPH 8

typedef __attribute__((ext_vector_type(8))) short bf16x8;
typedef __attribute__((ext_vector_type(4))) float f32x4;

constexpr unsigned ENC_NEGINF = 0x007FFFFFu;  // enc(-inf)

__device__ __forceinline__ unsigned enc_f(float f) {
  unsigned u = __float_as_uint(f);
  return (u & 0x80000000u) ? ~u : (u | 0x80000000u);
}
__device__ __forceinline__ float dec_f(unsigned k) {
  unsigned u = (k & 0x80000000u) ? (k & 0x7FFFFFFFu) : ~k;
  return __uint_as_float(u);
}
__device__ __forceinline__ float sigm(float x) { return 1.f / (1.f + __expf(-x)); }
__device__ __forceinline__ unsigned short f2bf(float f) {  // RNE f32->bf16
  unsigned u = __float_as_uint(f);
  u += 0x7FFFu + ((u >> 16) & 1u);
  return (unsigned short)(u >> 16);
}
__device__ __forceinline__ float bf2f(unsigned short u) {
  return __uint_as_float(((unsigned)u) << 16);
}
__device__ __forceinline__ float bflo(unsigned u) { return __uint_as_float(u << 16); }
__device__ __forceinline__ float bfhi(unsigned u) { return __uint_as_float(u & 0xffff0000u); }

// load 8 consecutive f32 (32B-aligned) -> bf16x8
__device__ __forceinline__ bf16x8 cvt8(const float* __restrict__ p) {
  float4 a = *(const float4*)p;
  float4 b = *(const float4*)(p + 4);
  bf16x8 r;
  r[0] = (short)f2bf(a.x); r[1] = (short)f2bf(a.y);
  r[2] = (short)f2bf(a.z); r[3] = (short)f2bf(a.w);
  r[4] = (short)f2bf(b.x); r[5] = (short)f2bf(b.y);
  r[6] = (short)f2bf(b.z); r[7] = (short)f2bf(b.w);
  return r;
}

// ---------------- generic fill ----------------
__global__ void k_fill_u32(unsigned* __restrict__ p, unsigned v, long long n) {
  long long i = (long long)blockIdx.x * blockDim.x + threadIdx.x;
  long long st = (long long)gridDim.x * blockDim.x;
  for (; i < n; i += st) p[i] = v;
}

// ---------------- CSR build (dst-sorted edge lists) ----------------
__global__ void k_deg(const int* __restrict__ dst, unsigned* __restrict__ deg, int E) {
  int i = blockIdx.x * blockDim.x + threadIdx.x;
  int st = gridDim.x * blockDim.x;
  for (; i < E; i += st) atomicAdd(&deg[dst[i]], 1u);
}

__global__ __launch_bounds__(1024) void k_scan(
    const unsigned* __restrict__ deg, unsigned* __restrict__ rowptr,
    unsigned* __restrict__ cursor, int N) {
  __shared__ unsigned part[1024];
  int t = threadIdx.x;
  int per = (N + 1023) >> 10;
  int s0 = t * per, s1 = min(N, s0 + per);
  unsigned s = 0;
  for (int i = s0; i < s1; ++i) s += deg[i];
  part[t] = s;
  __syncthreads();
  for (int off = 1; off < 1024; off <<= 1) {
    unsigned v = (t >= off) ? part[t - off] : 0u;
    __syncthreads();
    part[t] += v;
    __syncthreads();
  }
  unsigned base = (t == 0) ? 0u : part[t - 1];
  for (int i = s0; i < s1; ++i) {
    rowptr[i] = base;
    cursor[i] = base;
    base += deg[i];
  }
  if (t == 1023) rowptr[N] = part[1023];
}

__global__ void k_scatter(const int* __restrict__ dst, unsigned* __restrict__ cursor,
                          int* __restrict__ eidb, int E) {
  int i = blockIdx.x * blockDim.x + threadIdx.x;
  int st = gridDim.x * blockDim.x;
  for (; i < E; i += st) {
    unsigned p = atomicAdd(&cursor[dst[i]], 1u);
    eidb[p] = i;
  }
}

// srcP[r] = src[eidb[r]], dstP[r] = dst[eidb[r]]
__global__ void k_permidx(const int* __restrict__ eidb, const int* __restrict__ src,
                          const int* __restrict__ dst, int* __restrict__ srcP,
                          int* __restrict__ dstP, int E) {
  int i = blockIdx.x * blockDim.x + threadIdx.x;
  int st = gridDim.x * blockDim.x;
  for (; i < E; i += st) {
    int e = eidb[i];
    srcP[i] = src[e];
    dstP[i] = dst[e];
  }
}

// ---------------- weight pre-conversion to MFMA fragment order ----------------
// 0-2 U, 3-5 V, 6-8 A, 9-11 B, 12-14 C, 15 gsw, 16 gdw, 17 Ow, 18 W1[:,128:256], 19 W1[:,256:384]
__global__ __launch_bounds__(512) void k_wconv(
    const float* __restrict__ Us, const float* __restrict__ Vs,
    const float* __restrict__ As, const float* __restrict__ Bs,
    const float* __restrict__ Cs, const float* __restrict__ gsw,
    const float* __restrict__ gdw, const float* __restrict__ Ow,
    const float* __restrict__ W1, short* __restrict__ out) {
  int b = blockIdx.x;
  const float* W;
  int ldw = DF;
  if (b < 3) W = Us + b * 16384;
  else if (b < 6) W = Vs + (b - 3) * 16384;
  else if (b < 9) W = As + (b - 6) * 16384;
  else if (b < 12) W = Bs + (b - 9) * 16384;
  else if (b < 15) W = Cs + (b - 12) * 16384;
  else if (b == 15) W = gsw;
  else if (b == 16) W = gdw;
  else if (b == 17) W = Ow;
  else if (b == 18) { W = W1 + 128; ldw = 384; }
  else { W = W1 + 256; ldw = 384; }
  short* o = out + (size_t)b * 2048 * 8;
  for (int s = threadIdx.x; s < 2048; s += 512) {
    int ct = s >> 8, ks = (s >> 6) & 3, l = s & 63;
    int row = ct * 16 + (l & 15), k0 = ks * 32 + (l >> 4) * 8;
    *(bf16x8*)&o[s * 8] = cvt8(W + (size_t)row * ldw + k0);
  }
}

// ---------------- embeddings ----------------
__global__ __launch_bounds__(128) void k_node_embed(
    const float* __restrict__ hin, const float* __restrict__ w,
    const float* __restrict__ b, float* __restrict__ h0, int rows) {
  __shared__ float Wt[64 * DF];
  __shared__ float ar[4][64];
  int tid = threadIdx.x;
  for (int i = tid; i < 64 * DF; i += 128) Wt[(i & 63) * DF + (i >> 6)] = w[i];
  float bb = b[tid];
  __syncthreads();
  for (int r0 = blockIdx.x * 4; r0 < rows; r0 += gridDim.x * 4) {
    for (int i = tid; i < 256; i += 128) ar[i >> 6][i & 63] = hin[(size_t)r0 * 64 + i];
    __syncthreads();
    float a0 = bb, a1 = bb, a2 = bb, a3 = bb;
#pragma unroll 8
    for (int k = 0; k < 64; ++k) {
      float wv = Wt[k * DF + tid];
      a0 = fmaf(ar[0][k], wv, a0); a1 = fmaf(ar[1][k], wv, a1);
      a2 = fmaf(ar[2][k], wv, a2); a3 = fmaf(ar[3][k], wv, a3);
    }
    h0[(size_t)r0 * DF + tid] = a0;
    h0[(size_t)(r0 + 1) * DF + tid] = a1;
    h0[(size_t)(r0 + 2) * DF + tid] = a2;
    h0[(size_t)(r0 + 3) * DF + tid] = a3;
    __syncthreads();
  }
}

// permuted edge embed: slot r holds edge eidb[r]
__global__ __launch_bounds__(128) void k_edge_embed(
    const float* __restrict__ ein, const int* __restrict__ eidb,
    const float* __restrict__ w, const float* __restrict__ b,
    unsigned short* __restrict__ e0u, int rows) {
  __shared__ float Wt[16 * DF];
  __shared__ float ar[4][16];
  int tid = threadIdx.x;
  for (int i = tid; i < 16 * DF; i += 128) Wt[(i & 15) * DF + (i >> 4)] = w[i];
  float bb = b[tid];
  __syncthreads();
  for (int r0 = blockIdx.x * 4; r0 < rows; r0 += gridDim.x * 4) {
    if (tid < 64) {
      int e = eidb[r0 + (tid >> 4)];
      ar[tid >> 4][tid & 15] = ein[(size_t)e * 16 + (tid & 15)];
    }
    __syncthreads();
    float a0 = bb, a1 = bb, a2 = bb, a3 = bb;
#pragma unroll
    for (int k = 0; k < 16; ++k) {
      float wv = Wt[k * DF + tid];
      a0 = fmaf(ar[0][k], wv, a0); a1 = fmaf(ar[1][k], wv, a1);
      a2 = fmaf(ar[2][k], wv, a2); a3 = fmaf(ar[3][k], wv, a3);
    }
    e0u[(size_t)r0 * DF + tid] = f2bf(a0);
    e0u[(size_t)(r0 + 1) * DF + tid] = f2bf(a1);
    e0u[(size_t)(r0 + 2) * DF + tid] = f2bf(a2);
    e0u[(size_t)(r0 + 3) * DF + tid] = f2bf(a3);
    __syncthreads();
  }
}

// ---------------- MFMA [rows,128] @ W^T (+bias), frag weights, f32 input ----------------
template <int OUTBF>
__global__ __launch_bounds__(512) void k_gemm_mfma(
    const float* __restrict__ A, const short* __restrict__ Wf,
    const float* __restrict__ bias, void* __restrict__ outv, int rows) {
  __shared__ short Wb[2048 * 8];  // 32 KB
  int tid = threadIdx.x;
  for (int s = tid; s < 2048; s += 512)
    *(bf16x8*)&Wb[s * 8] = *(const bf16x8*)&Wf[(size_t)s * 8];
  __syncthreads();
  float* outf = (float*)outv;
  unsigned short* outb = (unsigned short*)outv;
  int wid = tid >> 6, lane = tid & 63, q = lane >> 4, m = lane & 15;
  int ntiles = (rows + 127) >> 7;
  for (int t = blockIdx.x; t < ntiles; t += gridDim.x) {
    int r0 = t * 128 + wid * 16;
    int rr = r0 + m;
    if (rr >= rows) rr = rows - 1;
    const float* ap = A + (size_t)rr * DF + q * 8;
    bf16x8 a[4];
#pragma unroll
    for (int ks = 0; ks < 4; ++ks) a[ks] = cvt8(ap + 32 * ks);
#pragma unroll
    for (int ct = 0; ct < 8; ++ct) {
      f32x4 acc = {0.f, 0.f, 0.f, 0.f};
#pragma unroll
      for (int ks = 0; ks < 4; ++ks) {
        bf16x8 b = *(const bf16x8*)&Wb[((ct * 4 + ks) * 64 + lane) * 8];
        acc = __builtin_amdgcn_mfma_f32_16x16x32_bf16(a[ks], b, acc, 0, 0, 0);
      }
      int col = ct * 16 + m;
      float bb = bias ? bias[col] : 0.f;
#pragma unroll
      for (int j = 0; j < 4; ++j) {
        int row = r0 + q * 4 + j;
        if (row < rows) {
          if (OUTBF) outb[(size_t)row * DF + col] = f2bf(acc[j] + bb);
          else outf[(size_t)row * DF + col] = acc[j] + bb;
        }
      }
    }
  }
}

// same, bf16 input
__global__ __launch_bounds__(512) void k_gemmb_mfma(
    const unsigned short* __restrict__ A, const short* __restrict__ Wf,
    unsigned short* __restrict__ outb, int rows) {
  __shared__ short Wb[2048 * 8];
  int tid = threadIdx.x;
  for (int s = tid; s < 2048; s += 512)
    *(bf16x8*)&Wb[s * 8] = *(const bf16x8*)&Wf[(size_t)s * 8];
  __syncthreads();
  int wid = tid >> 6, lane = tid & 63, q = lane >> 4, m = lane & 15;
  int ntiles = (rows + 127) >> 7;
  for (int t = blockIdx.x; t < ntiles; t += gridDim.x) {
    int r0 = t * 128 + wid * 16;
    int rr = r0 + m;
    if (rr >= rows) rr = rows - 1;
    const unsigned short* ap = A + (size_t)rr * DF + q * 8;
    bf16x8 a[4];
#pragma unroll
    for (int ks = 0; ks < 4; ++ks) a[ks] = *(const bf16x8*)(ap + 32 * ks);
#pragma unroll
    for (int ct = 0; ct < 8; ++ct) {
      f32x4 acc = {0.f, 0.f, 0.f, 0.f};
#pragma unroll
      for (int ks = 0; ks < 4; ++ks) {
        bf16x8 b = *(const bf16x8*)&Wb[((ct * 4 + ks) * 64 + lane) * 8];
        acc = __builtin_amdgcn_mfma_f32_16x16x32_bf16(a[ks], b, acc, 0, 0, 0);
      }
      int col = ct * 16 + m;
#pragma unroll
      for (int j = 0; j < 4; ++j) {
        int row = r0 + q * 4 + j;
        if (row < rows) outb[(size_t)row * DF + col] = f2bf(acc[j]);
      }
    }
  }
}

// ---------------- fused 4-output node GEMM (V,U,B,C) ----------------
__global__ __launch_bounds__(512) void k_gemm4_mfma(
    const float* __restrict__ h0, const short* __restrict__ Vf,
    const short* __restrict__ Uf, const short* __restrict__ Bf,
    const short* __restrict__ Cf, unsigned short* __restrict__ hVb,
    float* __restrict__ hU, unsigned short* __restrict__ hBb,
    unsigned short* __restrict__ hCb, int rows) {
  __shared__ short Wl[4 * 2048 * 8];  // 128 KB
  int tid = threadIdx.x;
  for (int s = tid; s < 2048; s += 512) {
    *(bf16x8*)&Wl[(size_t)s * 8] = *(const bf16x8*)&Vf[(size_t)s * 8];
    *(bf16x8*)&Wl[(size_t)(2048 + s) * 8] = *(const bf16x8*)&Uf[(size_t)s * 8];
    *(bf16x8*)&Wl[(size_t)(4096 + s) * 8] = *(const bf16x8*)&Bf[(size_t)s * 8];
    *(bf16x8*)&Wl[(size_t)(6144 + s) * 8] = *(const bf16x8*)&Cf[(size_t)s * 8];
  }
  __syncthreads();
  int wid = tid >> 6, lane = tid & 63, q = lane >> 4, m = lane & 15;
  int ntiles = (rows + 127) >> 7;
  for (int t = blockIdx.x; t < ntiles; t += gridDim.x) {
    int r0 = t * 128 + wid * 16;
    int rr = r0 + m;
    if (rr >= rows) rr = rows - 1;
    const float* ap = h0 + (size_t)rr * DF + q * 8;
    bf16x8 a[4];
#pragma unroll
    for (int ks = 0; ks < 4; ++ks) a[ks] = cvt8(ap + 32 * ks);
#pragma unroll
    for (int w = 0; w < 4; ++w) {
#pragma unroll
      for (int ct = 0; ct < 8; ++ct) {
        f32x4 acc = {0.f, 0.f, 0.f, 0.f};
#pragma unroll
        for (int ks = 0; ks < 4; ++ks) {
          bf16x8 b = *(const bf16x8*)&Wl[((w * 2048) + (ct * 4 + ks) * 64 + lane) * 8];
          acc = __builtin_amdgcn_mfma_f32_16x16x32_bf16(a[ks], b, acc, 0, 0, 0);
        }
        int col = ct * 16 + m;
#pragma unroll
        for (int j = 0; j < 4; ++j) {
          int row = r0 + q * 4 + j;
          if (row < rows) {
            if (w == 1) hU[(size_t)row * DF + col] = acc[j];
            else {
              unsigned short v = f2bf(acc[j]);
              unsigned short* o = (w == 0) ? hVb : ((w == 2) ? hBb : hCb);
              o[(size_t)row * DF + col] = v;
            }
          }
        }
      }
    }
  }
}

// ======== barrier-free swapped edge passes (mfma(W, e): lane owns ONE edge) ========
#define EDGE_MFMA_BODY                                                                 \
  const unsigned short* ep = e0u + (size_t)ec * DF + q * 8;                            \
  bf16x8 bv0 = *(const bf16x8*)(ep);                                                   \
  bf16x8 bv1 = *(const bf16x8*)(ep + 32);                                              \
  bf16x8 bv2 = *(const bf16x8*)(ep + 64);                                              \
  bf16x8 bv3 = *(const bf16x8*)(ep + 96);                                              \
  f32x4 c0 = {0.f, 0.f, 0.f, 0.f}, c1 = c0, c2 = c0, c3 = c0;                          \
  f32x4 c4 = c0, c5 = c0, c6 = c0, c7 = c0;                                            \
  _Pragma("unroll") for (int ks = 0; ks < 4; ++ks) {                                   \
    bf16x8 bv = (ks == 0) ? bv0 : (ks == 1) ? bv1 : (ks == 2) ? bv2 : bv3;             \
    c0 = __builtin_amdgcn_mfma_f32_16x16x32_bf16(*(const bf16x8*)&Wb[((0 * 4 + ks) * 64 + lane) * 8], bv, c0, 0, 0, 0); \
    c1 = __builtin_amdgcn_mfma_f32_16x16x32_bf16(*(const bf16x8*)&Wb[((1 * 4 + ks) * 64 + lane) * 8], bv, c1, 0, 0, 0); \
    c2 = __builtin_amdgcn_mfma_f32_16x16x32_bf16(*(const bf16x8*)&Wb[((2 * 4 + ks) * 64 + lane) * 8], bv, c2, 0, 0, 0); \
    c3 = __builtin_amdgcn_mfma_f32_16x16x32_bf16(*(const bf16x8*)&Wb[((3 * 4 + ks) * 64 + lane) * 8], bv, c3, 0, 0, 0); \
    c4 = __builtin_amdgcn_mfma_f32_16x16x32_bf16(*(const bf16x8*)&Wb[((4 * 4 + ks) * 64 + lane) * 8], bv, c4, 0, 0, 0); \
    c5 = __builtin_amdgcn_mfma_f32_16x16x32_bf16(*(const bf16x8*)&Wb[((5 * 4 + ks) * 64 + lane) * 8], bv, c5, 0, 0, 0); \
    c6 = __builtin_amdgcn_mfma_f32_16x16x32_bf16(*(const bf16x8*)&Wb[((6 * 4 + ks) * 64 + lane) * 8], bv, c6, 0, 0, 0); \
    c7 = __builtin_amdgcn_mfma_f32_16x16x32_bf16(*(const bf16x8*)&Wb[((7 * 4 + ks) * 64 + lane) * 8], bv, c7, 0, 0, 0); \
  }

// stats pass
__global__ __launch_bounds__(512) void k_edge_xs(
    const unsigned short* __restrict__ e0u, const short* __restrict__ Af,
    const unsigned short* __restrict__ hBb, const unsigned short* __restrict__ hCb,
    const int* __restrict__ srcP, const int* __restrict__ dstP,
    float* __restrict__ stat, int Eg) {
  __shared__ short Wb[2048 * 8];  // 32 KB
  __shared__ float ls[256];
  int tid = threadIdx.x;
  for (int s = tid; s < 2048; s += 512)
    *(bf16x8*)&Wb[s * 8] = *(const bf16x8*)&Af[(size_t)s * 8];
  if (tid < 256) ls[tid] = 0.f;
  int wid = tid >> 6, lane = tid & 63, q = lane >> 4, m = lane & 15;
  int g = blockIdx.x & 7, sub = blockIdx.x >> 3, nsub = gridDim.x >> 3;
  int gbase = g * Eg, gend = gbase + Eg;
  int tpg = (Eg + 127) >> 7;
  float ps[32], pq[32];
#pragma unroll
  for (int i = 0; i < 32; ++i) { ps[i] = 0.f; pq[i] = 0.f; }
  __syncthreads();
  for (int t = sub; t < tpg; t += nsub) {
    int r0 = gbase + t * 128 + wid * 16;
    int edge = r0 + m;
    bool ok = edge < gend;
    int ec = ok ? edge : gend - 1;
    EDGE_MFMA_BODY
    if (ok) {
      int sidx = srcP[ec], didx = dstP[ec];
      const unsigned short* pb = hBb + (size_t)didx * DF + q * 4;
      const unsigned short* pc = hCb + (size_t)sidx * DF + q * 4;
#pragma unroll
      for (int ct = 0; ct < 8; ++ct) {
        f32x4 cc = (ct == 0) ? c0 : (ct == 1) ? c1 : (ct == 2) ? c2 : (ct == 3) ? c3
                   : (ct == 4) ? c4 : (ct == 5) ? c5 : (ct == 6) ? c6 : c7;
        ushort4 hb = *(const ushort4*)(pb + ct * 16);
        ushort4 hc = *(const ushort4*)(pc + ct * 16);
        float x0 = cc[0] + bf2f(hb.x) + bf2f(hc.x);
        float x1 = cc[1] + bf2f(hb.y) + bf2f(hc.y);
        float x2 = cc[2] + bf2f(hb.z) + bf2f(hc.z);
        float x3 = cc[3] + bf2f(hb.w) + bf2f(hc.w);
        ps[ct * 4 + 0] += x0; pq[ct * 4 + 0] += x0 * x0;
        ps[ct * 4 + 1] += x1; pq[ct * 4 + 1] += x1 * x1;
        ps[ct * 4 + 2] += x2; pq[ct * 4 + 2] += x2 * x2;
        ps[ct * 4 + 3] += x3; pq[ct * 4 + 3] += x3 * x3;
      }
    }
  }
#pragma unroll
  for (int i = 0; i < 32; ++i) {
    float s = ps[i], sq = pq[i];
    s += __shfl_xor(s, 1, 64); sq += __shfl_xor(sq, 1, 64);
    s += __shfl_xor(s, 2, 64); sq += __shfl_xor(sq, 2, 64);
    s += __shfl_xor(s, 4, 64); sq += __shfl_xor(sq, 4, 64);
    s += __shfl_xor(s, 8, 64); sq += __shfl_xor(sq, 8, 64);
    if (m == 0) {
      int feat = (i >> 2) * 16 + q * 4 + (i & 3);
      atomicAdd(&ls[feat], s);
      atomicAdd(&ls[128 + feat], sq);
    }
  }
  __syncthreads();
  if (tid < 128) {
    atomicAdd(&stat[512 + tid], ls[tid]);
    atomicAdd(&stat[640 + tid], ls[128 + tid]);
  }
}

// apply pass
__global__ __launch_bounds__(512) void k_edge_xa(
    unsigned short* __restrict__ e0u, const short* __restrict__ Af,
    const unsigned short* __restrict__ hBb, const unsigned short* __restrict__ hCb,
    const int* __restrict__ srcP, const int* __restrict__ dstP,
    const float* __restrict__ stat, int Eg) {
  __shared__ short Wb[2048 * 8];  // 32 KB
  int tid = threadIdx.x;
  for (int s = tid; s < 2048; s += 512)
    *(bf16x8*)&Wb[s * 8] = *(const bf16x8*)&Af[(size_t)s * 8];
  int wid = tid >> 6, lane = tid & 63, q = lane >> 4, m = lane & 15;
  float mm[32], iv[32];
#pragma unroll
  for (int ct = 0; ct < 8; ++ct)
#pragma unroll
    for (int j = 0; j < 4; ++j) {
      int f = ct * 16 + q * 4 + j;
      mm[ct * 4 + j] = stat[768 + f];
      iv[ct * 4 + j] = stat[896 + f];
    }
  int g = blockIdx.x & 7, sub = blockIdx.x >> 3, nsub = gridDim.x >> 3;
  int gbase = g * Eg, gend = gbase + Eg;
  int tpg = (Eg + 127) >> 7;
  __syncthreads();
  for (int t = sub; t < tpg; t += nsub) {
    int r0 = gbase + t * 128 + wid * 16;
    int edge = r0 + m;
    bool ok = edge < gend;
    int ec = ok ? edge : gend - 1;
    EDGE_MFMA_BODY
    if (ok) {
      int sidx = srcP[ec], didx = dstP[ec];
      const unsigned short* pb = hBb + (size_t)didx * DF + q * 4;
      const unsigned short* pc = hCb + (size_t)sidx * DF + q * 4;
      unsigned short* pe = e0u + (size_t)ec * DF + q * 4;
#pragma unroll
      for (int ct = 0; ct < 8; ++ct) {
        f32x4 cc = (ct == 0) ? c0 : (ct == 1) ? c1 : (ct == 2) ? c2 : (ct == 3) ? c3
                   : (ct == 4) ? c4 : (ct == 5) ? c5 : (ct == 6) ? c6 : c7;
        ushort4 hb = *(const ushort4*)(pb + ct * 16);
        ushort4 hc = *(const ushort4*)(pc + ct * 16);
        ushort4 eo = *(const ushort4*)(pe + ct * 16);
        float x0 = cc[0] + bf2f(hb.x) + bf2f(hc.x);
        float x1 = cc[1] + bf2f(hb.y) + bf2f(hc.y);
        float x2 = cc[2] + bf2f(hb.z) + bf2f(hc.z);
        float x3 = cc[3] + bf2f(hb.w) + bf2f(hc.w);
        ushort4 nv;
        nv.x = f2bf(bf2f(eo.x) + fmaxf((x0 - mm[ct * 4 + 0]) * iv[ct * 4 + 0], 0.f));
        nv.y = f2bf(bf2f(eo.y) + fmaxf((x1 - mm[ct * 4 + 1]) * iv[ct * 4 + 1], 0.f));
        nv.z = f2bf(bf2f(eo.z) + fmaxf((x2 - mm[ct * 4 + 2]) * iv[ct * 4 + 2], 0.f));
        nv.w = f2bf(bf2f(eo.w) + fmaxf((x3 - mm[ct * 4 + 3]) * iv[ct * 4 + 3], 0.f));
        *(ushort4*)(pe + ct * 16) = nv;
      }
    }
  }
}

// ---------------- windowed segmented max (edge-major, dst-sorted runs) ----------------
// wave handles 64 consecutive edge slots; flush running max on dst change (wave-uniform).
#define FLUSH_MAX()                                                        \
  {                                                                        \
    atomicMax(&agg[(size_t)curD * DF + 2 * lane], enc_f(m0));              \
    atomicMax(&agg[(size_t)curD * DF + 2 * lane + 1], enc_f(m1));          \
    m0 = -3.4e38f; m1 = -3.4e38f;                                          \
  }

__global__ __launch_bounds__(256) void k_edge_max2(
    const unsigned short* __restrict__ hVb, const unsigned short* __restrict__ e0u,
    const int* __restrict__ srcP, const int* __restrict__ dstP,
    unsigned* __restrict__ agg, int Eg) {
  int tid = threadIdx.x, wid = tid >> 6, lane = tid & 63;
  int g = blockIdx.x & 7, sub = blockIdx.x >> 3, nsub = gridDim.x >> 3;
  int gbase = g * Eg;
  int nwin = (Eg + 63) >> 6;
  for (int w = sub * 4 + wid; w < nwin; w += nsub * 4) {
    int base = gbase + (w << 6);
    int cnt = min(64, gbase + Eg - base);
    int li = base + ((lane < cnt) ? lane : cnt - 1);
    int myS = srcP[li];
    int myD = dstP[li];
    int curD = __shfl(myD, 0, 64);
    float m0 = -3.4e38f, m1 = -3.4e38f;
    int j = 0;
    for (; j + 4 <= cnt; j += 4) {
      int s0 = __shfl(myS, j, 64), s1 = __shfl(myS, j + 1, 64);
      int s2 = __shfl(myS, j + 2, 64), s3 = __shfl(myS, j + 3, 64);
      int d0 = __shfl(myD, j, 64), d1 = __shfl(myD, j + 1, 64);
      int d2 = __shfl(myD, j + 2, 64), d3 = __shfl(myD, j + 3, 64);
      unsigned h0 = *(const unsigned*)&hVb[(size_t)s0 * DF + 2 * lane];
      unsigned h1 = *(const unsigned*)&hVb[(size_t)s1 * DF + 2 * lane];
      unsigned h2 = *(const unsigned*)&hVb[(size_t)s2 * DF + 2 * lane];
      unsigned h3 = *(const unsigned*)&hVb[(size_t)s3 * DF + 2 * lane];
      unsigned v0 = *(const unsigned*)&e0u[(size_t)(base + j) * DF + 2 * lane];
      unsigned v1 = *(const unsigned*)&e0u[(size_t)(base + j + 1) * DF + 2 * lane];
      unsigned v2 = *(const unsigned*)&e0u[(size_t)(base + j + 2) * DF + 2 * lane];
      unsigned v3 = *(const unsigned*)&e0u[(size_t)(base + j + 3) * DF + 2 * lane];
      float a0 = bflo(h0) * sigm(bflo(v0)), b0 = bfhi(h0) * sigm(bfhi(v0));
      float a1 = bflo(h1) * sigm(bflo(v1)), b1 = bfhi(h1) * sigm(bfhi(v1));
      float a2 = bflo(h2) * sigm(bflo(v2)), b2 = bfhi(h2) * sigm(bfhi(v2));
      float a3 = bflo(h3) * sigm(bflo(v3)), b3 = bfhi(h3) * sigm(bfhi(v3));
      if (d0 != curD) { FLUSH_MAX(); curD = d0; }
      m0 = fmaxf(m0, a0); m1 = fmaxf(m1, b0);
      if (d1 != curD) { FLUSH_MAX(); curD = d1; }
      m0 = fmaxf(m0, a1); m1 = fmaxf(m1, b1);
      if (d2 != curD) { FLUSH_MAX(); curD = d2; }
      m0 = fmaxf(m0, a2); m1 = fmaxf(m1, b2);
      if (d3 != curD) { FLUSH_MAX(); curD = d3; }
      m0 = fmaxf(m0, a3); m1 = fmaxf(m1, b3);
    }
    for (; j < cnt; ++j) {
      int s = __shfl(myS, j, 64);
      int d = __shfl(myD, j, 64);
      unsigned hv = *(const unsigned*)&hVb[(size_t)s * DF + 2 * lane];
      unsigned ev = *(const unsigned*)&e0u[(size_t)(base + j) * DF + 2 * lane];
      float a = bflo(hv) * sigm(bflo(ev)), b = bfhi(hv) * sigm(bfhi(ev));
      if (d != curD) { FLUSH_MAX(); curD = d; }
      m0 = fmaxf(m0, a); m1 = fmaxf(m1, b);
    }
    atomicMax(&agg[(size_t)curD * DF + 2 * lane], enc_f(m0));
    atomicMax(&agg[(size_t)curD * DF + 2 * lane + 1], enc_f(m1));
  }
}

// ---------------- node finalize: hU += dec(agg); BN stats (streaming) ----------------
__global__ __launch_bounds__(256) void k_node_fin(
    float* __restrict__ hU, const unsigned* __restrict__ agg,
    float* __restrict__ stat, long long total) {
  __shared__ float ls[512];
  int tid = threadIdx.x;
  float ps = 0.f, pq = 0.f;
  long long i = (long long)blockIdx.x * 256 + tid;
  long long st = (long long)gridDim.x * 256;
  for (; i < total; i += st) {
    unsigned k = agg[i];
    float a = (k == ENC_NEGINF) ? 0.f : dec_f(k);
    float t = hU[i] + a;
    hU[i] = t;
    ps += t;
    pq += t * t;
  }
  ls[tid] = ps;
  ls[256 + tid] = pq;
  __syncthreads();
  if (tid < 128) {
    atomicAdd(&stat[tid], ls[tid] + ls[tid + 128]);
    atomicAdd(&stat[128 + tid], ls[256 + tid] + ls[256 + tid + 128]);
  }
}

// finalize BN stats
__global__ void k_bn_finalize(float* __restrict__ stat, float nN, float nE) {
  int tid = threadIdx.x;
  if (tid < 128) {
    float mean = stat[tid] / nN;
    float var = stat[128 + tid] / nN - mean * mean;
    stat[256 + tid] = mean;
    stat[384 + tid] = rsqrtf(fmaxf(var, 0.f) + 1e-5f);
  } else {
    int d = tid - 128;
    float mean = stat[512 + d] / nE;
    float var = stat[640 + d] / nE - mean * mean;
    stat[768 + d] = mean;
    stat[896 + d] = rsqrtf(fmaxf(var, 0.f) + 1e-5f);
  }
}

__global__ __launch_bounds__(256) void k_node_update(
    float* __restrict__ h0, const float* __restrict__ hU,
    const float* __restrict__ stat, long long total) {
  long long i = (long long)blockIdx.x * blockDim.x + threadIdx.x;
  long long st = (long long)gridDim.x * blockDim.x;
  for (; i < total; i += st) {
    int d = (int)(i & 127);
    float t = (hU[i] - stat[256 + d]) * stat[384 + d];
    h0[i] += fmaxf(t, 0.f);
  }
}

// ---------------- GATv2 score (permuted edge-major) ----------------
__global__ __launch_bounds__(256) void k_gat_score(
    const unsigned short* __restrict__ fsb, const unsigned short* __restrict__ fdb,
    const int* __restrict__ srcP, const int* __restrict__ dstP,
    const float* __restrict__ attn, float* __restrict__ score, int E) {
  long long i = (long long)blockIdx.x * blockDim.x + threadIdx.x;
  long long st = (long long)gridDim.x * blockDim.x;
  long long total = (long long)E * 8;
  for (; i < total; i += st) {
    int e = (int)(i >> 3), mh = (int)(i & 7);
    int s = srcP[e], dn = dstP[e];
    const unsigned short* ps = fsb + (size_t)s * DF + mh * 16;
    const unsigned short* pd = fdb + (size_t)dn * DF + mh * 16;
    const float* pa = attn + mh * 16;
    bf16x8 s0 = *(const bf16x8*)ps;
    bf16x8 s1 = *(const bf16x8*)(ps + 8);
    bf16x8 d0 = *(const bf16x8*)pd;
    bf16x8 d1 = *(const bf16x8*)(pd + 8);
    float acc = 0.f;
#pragma unroll
    for (int kk = 0; kk < 8; ++kk) {
      float z = bf2f((unsigned short)s0[kk]) + bf2f((unsigned short)d0[kk]);
      z = (z > 0.f) ? z : 0.2f * z;
      acc = fmaf(z, pa[kk], acc);
      float z2 = bf2f((unsigned short)s1[kk]) + bf2f((unsigned short)d1[kk]);
      z2 = (z2 > 0.f) ? z2 : 0.2f * z2;
      acc = fmaf(z2, pa[kk + 8], acc);
    }
    score[i] = acc;
  }
}

// ---------------- GATv2 node reduction (streamed scores) ----------------
__global__ __launch_bounds__(256) void k_gat_node(
    const float* __restrict__ score, const unsigned short* __restrict__ fsb,
    const int* __restrict__ srcP, const unsigned* __restrict__ rowptr,
    float* __restrict__ rst, int Ngr) {
  int tid = threadIdx.x, wid = tid >> 6, lane = tid & 63;
  int g = blockIdx.x & 7, sub = blockIdx.x >> 3, nsub = gridDim.x >> 3;
  int head = lane >> 3, slot = lane & 7;
  for (int nn = sub * 4 + wid; nn < Ngr; nn += nsub * 4) {
    int n = g * Ngr + nn;
    unsigned r0 = rowptr[n], r1 = rowptr[n + 1];
    float hm = -3.4e38f;
    for (unsigned r = r0 + slot; r < r1; r += 8)
      hm = fmaxf(hm, score[(size_t)r * 8 + head]);
#pragma unroll
    for (int mk = 1; mk < 8; mk <<= 1) hm = fmaxf(hm, __shfl_xor(hm, mk, 64));
    float dn = 0.f;
    for (unsigned r = r0 + slot; r < r1; r += 8)
      dn += __expf(score[(size_t)r * 8 + head] - hm);
#pragma unroll
    for (int mk = 1; mk < 8; mk <<= 1) dn += __shfl_xor(dn, mk, 64);
    float inv = (r1 > r0) ? 1.f / dn : 0.f;
    float a0 = 0.f, a1 = 0.f;
    for (unsigned rc = r0; rc < r1; rc += 64) {
      int batch = (int)min(64u, r1 - rc);
      int myS = srcP[rc + ((lane < batch) ? lane : 0)];
      int j = 0;
      for (; j + 4 <= batch; j += 4) {
        int s0 = __shfl(myS, j, 64), s1 = __shfl(myS, j + 1, 64);
        int s2 = __shfl(myS, j + 2, 64), s3 = __shfl(myS, j + 3, 64);
        float sc0 = score[(size_t)(rc + j) * 8 + head];
        float sc1 = score[(size_t)(rc + j + 1) * 8 + head];
        float sc2 = score[(size_t)(rc + j + 2) * 8 + head];
        float sc3 = score[(size_t)(rc + j + 3) * 8 + head];
        unsigned f0 = *(const unsigned*)&fsb[(size_t)s0 * DF + 2 * lane];
        unsigned f1 = *(const unsigned*)&fsb[(size_t)s1 * DF + 2 * lane];
        unsigned f2 = *(const unsigned*)&fsb[(size_t)s2 * DF + 2 * lane];
        unsigned f3 = *(const unsigned*)&fsb[(size_t)s3 * DF + 2 * lane];
        float w0 = __expf(sc0 - hm) * inv, w1 = __expf(sc1 - hm) * inv;
        float w2 = __expf(sc2 - hm) * inv, w3 = __expf(sc3 - hm) * inv;
        a0 = fmaf(w0, bflo(f0), a0); a1 = fmaf(w0, bfhi(f0), a1);
        a0 = fmaf(w1, bflo(f1), a0); a1 = fmaf(w1, bfhi(f1), a1);
        a0 = fmaf(w2, bflo(f2), a0); a1 = fmaf(w2, bfhi(f2), a1);
        a0 = fmaf(w3, bflo(f3), a0); a1 = fmaf(w3, bfhi(f3), a1);
      }
      for (; j < batch; ++j) {
        int s = __shfl(myS, j, 64);
        float w = __expf(score[(size_t)(rc + j) * 8 + head] - hm) * inv;
        unsigned fv = *(const unsigned*)&fsb[(size_t)s * DF + 2 * lane];
        a0 = fmaf(w, bflo(fv), a0);
        a1 = fmaf(w, bfhi(fv), a1);
      }
    }
    float2 o;
    o.x = a0; o.y = a1;
    *(float2*)&rst[(size_t)n * DF + 2 * lane] = o;
  }
}

// bias2 = O_b + gat_bias @ O_w^T
__global__ void k_bias2(const float* __restrict__ gat_bias,
                        const float* __restrict__ O_w,
                        const float* __restrict__ O_b, float* __restrict__ bias2) {
  int d = threadIdx.x;
  float acc = O_b[d];
  for (int k = 0; k < DF; ++k) acc = fmaf(gat_bias[k], O_w[(size_t)d * DF + k], acc);
  bias2[d] = acc;
}

// ---------------- readout ----------------
__global__ __launch_bounds__(128) void k_moy(
    const unsigned short* __restrict__ h2b, const int* __restrict__ ng,
    float* __restrict__ moy, float* __restrict__ cnt, int rows) {
  int tid = threadIdx.x;
  int per = (rows + gridDim.x - 1) / gridDim.x;
  int n0 = blockIdx.x * per;
  int n1 = min(rows, n0 + per);
  if (n0 >= n1) return;
  int cur = ng[n0];
  float acc = 0.f; int c = 0;
  for (int n = n0; n < n1; ++n) {
    int g = ng[n];
    if (g != cur) {
      atomicAdd(&moy[cur * DF + tid], acc);
      if (tid == 0) atomicAdd(&cnt[cur], (float)c);
      acc = 0.f; c = 0; cur = g;
    }
    acc += bf2f(h2b[(size_t)n * DF + tid]);
    ++c;
  }
  atomicAdd(&moy[cur * DF + tid], acc);
  if (tid == 0) atomicAdd(&cnt[cur], (float)c);
}

// P0[g] = W1[:,0:128] @ (moy_sum[g]/cnt[g]) + W1_b
__global__ void k_p0(const float* __restrict__ W1, const float* __restrict__ W1b_,
                     const float* __restrict__ moy, const float* __restrict__ cnt,
                     float* __restrict__ P0) {
  int g = blockIdx.x, d = threadIdx.x;
  float inv = 1.f / cnt[g];
  float acc = W1b_[d];
  for (int k = 0; k < DF; ++k) acc = fmaf(W1[(size_t)d * 384 + k], moy[g * DF + k] * inv, acc);
  P0[g * DF + d] = acc;
}

// ---------------- CSR head (permuted; out scatter via eidb) ----------------
__global__ __launch_bounds__(256) void k_head(
    const unsigned short* __restrict__ P1b, const unsigned short* __restrict__ P2b,
    const float* __restrict__ P0, const int* __restrict__ srcP,
    const unsigned* __restrict__ rowptr, const int* __restrict__ eidb,
    const float* __restrict__ W2, const float* __restrict__ W2b,
    float* __restrict__ out, int Ngr) {
  int tid = threadIdx.x, wid = tid >> 6, lane = tid & 63;
  int g = blockIdx.x & 7, sub = blockIdx.x >> 3, nsub = gridDim.x >> 3;
  float w2b = W2b[0];
  float w20 = W2[2 * lane], w21 = W2[2 * lane + 1];
  float b0 = P0[g * DF + 2 * lane], b1v = P0[g * DF + 2 * lane + 1];
  for (int nn = sub * 4 + wid; nn < Ngr; nn += nsub * 4) {
    int n = g * Ngr + nn;
    unsigned r0 = rowptr[n], r1 = rowptr[n + 1];
    if (r1 == r0) continue;
    unsigned p2 = *(const unsigned*)&P2b[(size_t)n * DF + 2 * lane];
    float base0 = b0 + bflo(p2);
    float base1 = b1v + bfhi(p2);
    for (unsigned rc = r0; rc < r1; rc += 64) {
      int cnt2 = (int)min(64u, r1 - rc);
      int myE = eidb[rc + ((lane < cnt2) ? lane : 0)];
      int myS = srcP[rc + ((lane < cnt2) ? lane : 0)];
      int j = 0;
      for (; j + 4 <= cnt2; j += 4) {
        int e0 = __shfl(myE, j, 64), e1 = __shfl(myE, j + 1, 64);
        int e2 = __shfl(myE, j + 2, 64), e3 = __shfl(myE, j + 3, 64);
        int s0 = __shfl(myS, j, 64), s1 = __shfl(myS, j + 1, 64);
        int s2 = __shfl(myS, j + 2, 64), s3 = __shfl(myS, j + 3, 64);
        unsigned u0 = *(const unsigned*)&P1b[(size_t)s0 * DF + 2 * lane];
        unsigned u1 = *(const unsigned*)&P1b[(size_t)s1 * DF + 2 * lane];
        unsigned u2 = *(const unsigned*)&P1b[(size_t)s2 * DF + 2 * lane];
        unsigned u3 = *(const unsigned*)&P1b[(size_t)s3 * DF + 2 * lane];
        float v0 = fmaxf(base0 + bflo(u0), 0.f) * w20 + fmaxf(base1 + bfhi(u0), 0.f) * w21;
        float v1 = fmaxf(base0 + bflo(u1), 0.f) * w20 + fmaxf(base1 + bfhi(u1), 0.f) * w21;
        float v2 = fmaxf(base0 + bflo(u2), 0.f) * w20 + fmaxf(base1 + bfhi(u2), 0.f) * w21;
        float v3 = fmaxf(base0 + bflo(u3), 0.f) * w20 + fmaxf(base1 + bfhi(u3), 0.f) * w21;
#pragma unroll
        for (int mk = 1; mk < 64; mk <<= 1) {
          v0 += __shfl_xor(v0, mk, 64);
          v1 += __shfl_xor(v1, mk, 64);
          v2 += __shfl_xor(v2, mk, 64);
          v3 += __shfl_xor(v3, mk, 64);
        }
        if (lane == 0) {
          out[e0] = sigm(v0 + w2b);
          out[e1] = sigm(v1 + w2b);
          out[e2] = sigm(v2 + w2b);
          out[e3] = sigm(v3 + w2b);
        }
      }
      for (; j < cnt2; ++j) {
        int e = __shfl(myE, j, 64);
        int s = __shfl(myS, j, 64);
        unsigned p1 = *(const unsigned*)&P1b[(size_t)s * DF + 2 * lane];
        float v = fmaxf(base0 + bflo(p1), 0.f) * w20 + fmaxf(base1 + bfhi(p1), 0.f) * w21;
#pragma unroll
        for (int mk = 1; mk < 64; mk <<= 1) v += __shfl_xor(v, mk, 64);
        if (lane == 0) out[e] = sigm(v + w2b);
      }
    }
  }
}

extern "C" void kernel_launch(void* const* d_in, const int* in_sizes, int n_in,
                              void* d_out, int out_size, void* d_ws, size_t ws_size,
                              hipStream_t stream) {
  const float* h_in = (const float*)d_in[0];
  const float* e_in = (const float*)d_in[1];
  const int* src = (const int*)d_in[2];
  const int* dst = (const int*)d_in[3];
  const int* node_graph = (const int*)d_in[4];
  const float* emb_n_w = (const float*)d_in[6];
  const float* emb_n_b = (const float*)d_in[7];
  const float* emb_e_w = (const float*)d_in[8];
  const float* emb_e_b = (const float*)d_in[9];
  const float* Us = (const float*)d_in[10];
  const float* Vs = (const float*)d_in[11];
  const float* As = (const float*)d_in[12];
  const float* Bs = (const float*)d_in[13];
  const float* Cs = (const float*)d_in[14];
  const float* gat_src_w = (const float*)d_in[15];
  const float* gat_src_b = (const float*)d_in[16];
  const float* gat_dst_w = (const float*)d_in[17];
  const float* gat_dst_b = (const float*)d_in[18];
  const float* gat_attn = (const float*)d_in[19];
  const float* gat_bias = (const float*)d_in[20];
  const float* O_w = (const float*)d_in[21];
  const float* O_b = (const float*)d_in[22];
  const float* W1_w = (const float*)d_in[23];
  const float* W1_b = (const float*)d_in[24];
  const float* W2_w = (const float*)d_in[25];
  const float* W2_b = (const float*)d_in[26];
  float* out = (float*)d_out;

  const int N = in_sizes[0] / 64;   // 30000
  const int E = in_sizes[1] / 16;   // 360000
  const int Eg = E / NGRAPH;        // 45000
  const int Ngr = N / NGRAPH;       // 3750

  auto rnd = [](size_t b) { return (b + 255) & ~(size_t)255; };
  const size_t sz_e0 = rnd((size_t)E * DF * 2);
  const size_t sz_node = rnd((size_t)N * DF * 4);
  const size_t sz_nodeb = rnd((size_t)N * DF * 2);
  const size_t sz_score = rnd((size_t)E * 8 * 4);
  const size_t sz_wfrag = rnd(20 * 2048 * 8 * 2);
  const size_t sz_rp = rnd((size_t)(N + 1) * 4);
  const size_t sz_eid = rnd((size_t)E * 4);
  const size_t sz_misc = rnd(4096 * 4);
  const size_t needed = sz_e0 + 3 * sz_node + 4 * sz_nodeb + sz_score + sz_wfrag +
                        3 * sz_rp + 3 * sz_eid + sz_misc;
  if (ws_size < needed) {
    k_fill_u32<<<256, 256, 0, stream>>>((unsigned*)out, 0xBF800000u, (long long)out_size);
    return;
  }

  char* wp = (char*)d_ws;
  auto alloc = [&](size_t bytes) { void* p = wp; wp += bytes; return p; };
  unsigned short* e0u = (unsigned short*)alloc(sz_e0);
  float* h0 = (float*)alloc(sz_node);
  float* hU = (float*)alloc(sz_node);
  float* rst = (float*)alloc(sz_node);  // doubles as agg (u32) during layers
  unsigned short* hVb = (unsigned short*)alloc(sz_nodeb);
  unsigned short* hBb = (unsigned short*)alloc(sz_nodeb);
  unsigned short* hCb = (unsigned short*)alloc(sz_nodeb);
  unsigned short* h2b = (unsigned short*)alloc(sz_nodeb);
  float* score = (float*)alloc(sz_score);
  short* wfrag = (short*)alloc(sz_wfrag);
  unsigned* rowptr = (unsigned*)alloc(sz_rp);
  unsigned* cursor = (unsigned*)alloc(sz_rp);
  unsigned* deg = (unsigned*)alloc(sz_rp);
  int* eidb = (int*)alloc(sz_eid);
  int* srcP = (int*)alloc(sz_eid);
  int* dstP = (int*)alloc(sz_eid);
  float* misc = (float*)alloc(sz_misc);
  float* stat = misc;                                     // [0,1024)
  float* bias2 = misc + 1024;                             // [1024,1152)
  float* moy = misc + 1152;                               // [1152,2176)
  float* cnt = misc + 2176;                               // [2176,2184)
  float* P0 = misc + 2304;                                // [2304,3328)
  unsigned short* P1b = e0u;  // alias: e0u dead after last layer
  unsigned short* P2b = e0u + (size_t)N * DF;
  unsigned* agg = (unsigned*)rst;

  auto WF = [&](int idx) { return wfrag + (size_t)idx * 2048 * 8; };

  // CSR build + permuted indices
  k_fill_u32<<<64, 256, 0, stream>>>(deg, 0u, N);
  k_deg<<<512, 256, 0, stream>>>(dst, deg, E);
  k_scan<<<1, 1024, 0, stream>>>(deg, rowptr, cursor, N);
  k_scatter<<<512, 256, 0, stream>>>(dst, cursor, eidb, E);
  k_permidx<<<512, 256, 0, stream>>>(eidb, src, dst, srcP, dstP, E);

  k_wconv<<<20, 512, 0, stream>>>(Us, Vs, As, Bs, Cs, gat_src_w, gat_dst_w, O_w,
                                  W1_w, wfrag);

  const int gN = (N + 127) / 128;
  k_node_embed<<<2048, 128, 0, stream>>>(h_in, emb_n_w, emb_n_b, h0, N);
  k_edge_embed<<<4096, 128, 0, stream>>>(e_in, eidb, emb_e_w, emb_e_b, e0u, E);

  for (int l = 0; l < 3; ++l) {
    k_gemm4_mfma<<<gN, 512, 0, stream>>>(h0, WF(3 + l), WF(l), WF(9 + l), WF(12 + l),
                                         hVb, hU, hBb, hCb, N);
    k_fill_u32<<<1024, 256, 0, stream>>>(agg, ENC_NEGINF, (long long)N * DF);
    k_fill_u32<<<4, 256, 0, stream>>>((unsigned*)stat, 0u, 1024);
    k_edge_max2<<<1024, 256, 0, stream>>>(hVb, e0u, srcP, dstP, agg, Eg);
    k_node_fin<<<1024, 256, 0, stream>>>(hU, agg, stat, (long long)N * DF);
    k_edge_xs<<<1024, 512, 0, stream>>>(e0u, WF(6 + l), hBb, hCb, srcP, dstP, stat, Eg);
    k_bn_finalize<<<1, 256, 0, stream>>>(stat, (float)N, (float)E);
    k_node_update<<<2048, 256, 0, stream>>>(h0, hU, stat, (long long)N * DF);
    k_edge_xa<<<1024, 512, 0, stream>>>(e0u, WF(6 + l), hBb, hCb, srcP, dstP, stat, Eg);
  }

  // GATv2: fs -> hVb, fd -> hBb
  k_gemm_mfma<1><<<gN, 512, 0, stream>>>(h0, WF(15), gat_src_b, hVb, N);
  k_gemm_mfma<1><<<gN, 512, 0, stream>>>(h0, WF(16), gat_dst_b, hBb, N);
  k_gat_score<<<2048, 256, 0, stream>>>(hVb, hBb, srcP, dstP, gat_attn, score, E);
  k_gat_node<<<2048, 256, 0, stream>>>(score, hVb, srcP, rowptr, rst, Ngr);
  k_bias2<<<1, 128, 0, stream>>>(gat_bias, O_w, O_b, bias2);
  k_gemm_mfma<1><<<gN, 512, 0, stream>>>(rst, WF(17), bias2, h2b, N);  // h2

  // readout + decomposed head
  k_fill_u32<<<2, 256, 0, stream>>>((unsigned*)moy, 0u, 1032);
  k_moy<<<128, 128, 0, stream>>>(h2b, node_graph, moy, cnt, N);
  k_p0<<<8, 128, 0, stream>>>(W1_w, W1_b, moy, cnt, P0);
  k_gemmb_mfma<<<gN, 512, 0, stream>>>(h2b, WF(18), P1b, N);
  k_gemmb_mfma<<<gN, 512, 0, stream>>>(h2b, WF(19), P2b, N);
  k_head<<<2048, 256, 0, stream>>>(P1b, P2b, P0, srcP, rowptr, eidb, W2_w, W2_b,
                                   out, Ngr);
}